// Round 1
// baseline (28582.861 us; speedup 1.0000x reference)
//
#include <hip/hip_runtime.h>

#define LEAKY(v) ((v) > 0.f ? (v) : 0.01f * (v))

// ---------------- style: s[b,ci] = latent_row[b] @ sw[:,ci] + sb[ci] ----------------
__global__ __launch_bounds__(256) void style_kernel(
    const float* __restrict__ lat, int latStride,
    const float* __restrict__ sw, const float* __restrict__ sb,
    int Cin, float* __restrict__ s_out)
{
  int b = blockIdx.x;
  const float* l = lat + (size_t)b * latStride;
  for (int ci = threadIdx.x; ci < Cin; ci += 256) {
    float acc = sb[ci];
    for (int k = 0; k < 512; k++) acc += l[k] * sw[(size_t)k * Cin + ci];
    s_out[b * 512 + ci] = acc;
  }
}

// ---------------- demod: d[b,co] = rsqrt(sum_{kt,ci} (w*s)^2 + 1e-8) ----------------
__global__ __launch_bounds__(256) void demod_kernel(
    const float* __restrict__ w, const float* __restrict__ s,
    int KK, int Cin, int Cout, float* __restrict__ d_out)
{
  int b = blockIdx.y;
  int co = blockIdx.x * 256 + threadIdx.x;
  if (co >= Cout) return;
  float acc = 0.f;
  for (int kt = 0; kt < KK; kt++) {
    for (int ci = 0; ci < Cin; ci++) {
      float wv = w[((size_t)(kt * Cin + ci)) * Cout + co];
      float sv = s[b * 512 + ci];
      float t = wv * sv;
      acc += t * t;
    }
  }
  d_out[b * 512 + co] = rsqrtf(acc + 1e-8f);
}

// ---------------- blur_up taps: 2x upsample + [1,3,3,1] FIR (separable) ----------------
__device__ inline void blur_taps(int o, int* r0, int* r1, float* w0, float* w1)
{
  if ((o & 1) == 0) { *r0 = (o >> 1) - 1; *w0 = 1.f; *r1 = (o >> 1); *w1 = 3.f; }
  else              { *r0 = (o - 1) >> 1; *w0 = 3.f; *r1 = ((o - 1) >> 1) + 1; *w1 = 1.f; }
}

__global__ __launch_bounds__(256) void blur_up_kernel(
    const float* __restrict__ x, int H, int W, int C, float* __restrict__ out)
{
  int b = blockIdx.y;
  int W2 = W * 2, H2 = H * 2;
  int pix = blockIdx.x;
  int oy = pix / W2, ox = pix % W2;
  int ry0, ry1, rx0, rx1; float wy0, wy1, wx0, wx1;
  blur_taps(oy, &ry0, &ry1, &wy0, &wy1);
  blur_taps(ox, &rx0, &rx1, &wx0, &wx1);
  bool vy0 = (ry0 >= 0 && ry0 < H), vy1 = (ry1 >= 0 && ry1 < H);
  bool vx0 = (rx0 >= 0 && rx0 < W), vx1 = (rx1 >= 0 && rx1 < W);
  const float* base = x + (size_t)b * H * W * C;
  float* ob = out + (((size_t)b * H2 + oy) * W2 + ox) * C;
  for (int c = threadIdx.x; c < C; c += 256) {
    float acc = 0.f;
    if (vy0) {
      const float* r = base + (size_t)(ry0 * W) * C;
      if (vx0) acc += wy0 * wx0 * r[(size_t)rx0 * C + c];
      if (vx1) acc += wy0 * wx1 * r[(size_t)rx1 * C + c];
    }
    if (vy1) {
      const float* r = base + (size_t)(ry1 * W) * C;
      if (vx0) acc += wy1 * wx0 * r[(size_t)rx0 * C + c];
      if (vx1) acc += wy1 * wx1 * r[(size_t)rx1 * C + c];
    }
    ob[c] = acc * (1.f / 16.f);
  }
}

// ---------------- 3x3 modulated conv (SAME). Block: 4 pixels x (<=512 couts) ----------------
__global__ __launch_bounds__(256) void modconv3x3_kernel(
    const float* __restrict__ x, size_t xBStride, int H, int W, int Cin, int cinShift, int Cout,
    const float* __restrict__ w, const float* __restrict__ bias,
    const float* __restrict__ s, const float* __restrict__ dmod,
    const float* __restrict__ noise, const float* __restrict__ ns,
    float* __restrict__ out, int doAct)
{
  extern __shared__ float lds[];
  const int tid = threadIdx.x;
  const int b = blockIdx.y;
  const int wb = W >> 2;
  const int row = blockIdx.x / wb;
  const int x0 = (blockIdx.x % wb) << 2;

  const float* xb = x + (size_t)b * xBStride;
  const float* sv = s + b * 512;

  // stage 3 rows x 6 cols x Cin patch, with style folded in
  const int tot = 18 << cinShift;
  for (int idx = tid; idx < tot; idx += 256) {
    int ci = idx & (Cin - 1);
    int t = idx >> cinShift;
    int col = t % 6;
    int ry = t / 6;
    int gy = row + ry - 1;
    int gx = x0 + col - 1;
    float v = 0.f;
    if (gy >= 0 && gy < H && gx >= 0 && gx < W)
      v = xb[((size_t)(gy * W + gx) << cinShift) + ci] * sv[ci];
    lds[idx] = v;
  }
  __syncthreads();

  float acc0[4] = {0.f, 0.f, 0.f, 0.f};
  float acc1[4] = {0.f, 0.f, 0.f, 0.f};
  const int co0 = tid;
  const int co1 = tid + 256;
  const bool a0 = co0 < Cout;
  const bool a1 = co1 < Cout;

  for (int kt = 0; kt < 9; kt++) {
    int ky = kt / 3, kx = kt % 3;
    const float* p = lds + ((ky * 6 + kx) << cinShift);
    const float* wp = w + ((size_t)(kt << cinShift)) * Cout;
    for (int ci = 0; ci < Cin; ci++) {
      float p0 = p[ci];
      float p1 = p[ci + (1 << cinShift)];
      float p2 = p[ci + (2 << cinShift)];
      float p3 = p[ci + (3 << cinShift)];
      const float* wr = wp + (size_t)ci * Cout;
      if (a0) {
        float wv = wr[co0];
        acc0[0] += p0 * wv; acc0[1] += p1 * wv; acc0[2] += p2 * wv; acc0[3] += p3 * wv;
      }
      if (a1) {
        float wv = wr[co1];
        acc1[0] += p0 * wv; acc1[1] += p1 * wv; acc1[2] += p2 * wv; acc1[3] += p3 * wv;
      }
    }
  }

  for (int slot = 0; slot < 2; slot++) {
    int co = slot ? co1 : co0;
    if (co >= Cout) break;
    float dm = dmod ? dmod[b * 512 + co] : 1.f;
    float bv = bias[co];
    float* accp = slot ? acc1 : acc0;
    for (int p = 0; p < 4; p++) {
      float v = accp[p] * dm + bv;
      if (noise) v += ns[0] * noise[b * 16 + row * 4 + (x0 + p)];
      if (doAct) v = LEAKY(v);
      out[((size_t)((b * H + row) * W) + (x0 + p)) * Cout + co] = v;
    }
  }
}

// ---------------- to_rgb: 1x1 modconv (no demod) + leaky + optional blur-up skip add ----------------
__global__ __launch_bounds__(64) void rgb_kernel(
    const float* __restrict__ y, int H, int W, int Cin,
    const float* __restrict__ w, const float* __restrict__ bias,
    const float* __restrict__ s, const float* __restrict__ prev,
    float* __restrict__ out)
{
  int b = blockIdx.y;
  int pix = blockIdx.x;
  int oy = pix / W, ox = pix % W;
  const float* xp = y + (((size_t)b * H + oy) * W + ox) * Cin;
  const float* sv = s + b * 512;
  float p0 = 0.f, p1 = 0.f, p2 = 0.f;
  for (int ci = threadIdx.x; ci < Cin; ci += 64) {
    float v = xp[ci] * sv[ci];
    p0 += v * w[ci * 3 + 0];
    p1 += v * w[ci * 3 + 1];
    p2 += v * w[ci * 3 + 2];
  }
  for (int off = 32; off > 0; off >>= 1) {
    p0 += __shfl_down(p0, off);
    p1 += __shfl_down(p1, off);
    p2 += __shfl_down(p2, off);
  }
  if (threadIdx.x == 0) {
    float r[3] = {p0 + bias[0], p1 + bias[1], p2 + bias[2]};
    float sk[3] = {0.f, 0.f, 0.f};
    if (prev) {
      int Hp = H >> 1, Wp = W >> 1;
      int ry0, ry1, rx0, rx1; float wy0, wy1, wx0, wx1;
      blur_taps(oy, &ry0, &ry1, &wy0, &wy1);
      blur_taps(ox, &rx0, &rx1, &wx0, &wx1);
      bool vy0 = (ry0 >= 0 && ry0 < Hp), vy1 = (ry1 >= 0 && ry1 < Hp);
      bool vx0 = (rx0 >= 0 && rx0 < Wp), vx1 = (rx1 >= 0 && rx1 < Wp);
      const float* base = prev + (size_t)b * Hp * Wp * 3;
      for (int c = 0; c < 3; c++) {
        float acc = 0.f;
        if (vy0 && vx0) acc += wy0 * wx0 * base[(size_t)(ry0 * Wp + rx0) * 3 + c];
        if (vy0 && vx1) acc += wy0 * wx1 * base[(size_t)(ry0 * Wp + rx1) * 3 + c];
        if (vy1 && vx0) acc += wy1 * wx0 * base[(size_t)(ry1 * Wp + rx0) * 3 + c];
        if (vy1 && vx1) acc += wy1 * wx1 * base[(size_t)(ry1 * Wp + rx1) * 3 + c];
        sk[c] = acc * (1.f / 16.f);
      }
    }
    float* ob = out + (((size_t)b * H + oy) * W + ox) * 3;
    for (int c = 0; c < 3; c++) ob[c] = LEAKY(r[c]) + sk[c];
  }
}

extern "C" void kernel_launch(void* const* d_in, const int* in_sizes, int n_in,
                              void* d_out, int out_size, void* d_ws, size_t ws_size,
                              hipStream_t stream)
{
  auto F = [&](int k) { return (const float*)d_in[k]; };
  const float* latents = F(0);
  const float* cnst = F(1);
  const float* w0 = F(2);  const float* b0 = F(3);  const float* sw0 = F(4);  const float* sb0 = F(5);
  const float* ns0 = F(6); const float* noise0 = F(7);
  const float* wr0 = F(8); const float* br0 = F(9); const float* swr0 = F(10); const float* sbr0 = F(11);
  const float *wu[4], *bu[4], *swu[4], *sbu[4];
  const float *wc[4], *bc[4], *swc[4], *sbc[4];
  const float *wr[4], *br_[4], *swr[4], *sbr[4];
  int k = 12;
  for (int l = 0; l < 4; l++) {
    wu[l] = F(k++); bu[l] = F(k++); swu[l] = F(k++); sbu[l] = F(k++);
    wc[l] = F(k++); bc[l] = F(k++); swc[l] = F(k++); sbc[l] = F(k++);
    wr[l] = F(k++); br_[l] = F(k++); swr[l] = F(k++); sbr[l] = F(k++);
  }

  float* ws = (float*)d_ws;
  float* S = ws;                          // 14 convs * (2*512)
  float* D = S + 14 * 1024;               // 9 demod convs * (2*512)
  float* bufA = D + 9 * 1024;             // 2*64*64*512 floats
  float* bufB = bufA + 2 * 64 * 64 * 512;
  float* rgbA = bufB + 2 * 64 * 64 * 512; // 2*64*64*3
  float* rgbB = rgbA + 2 * 64 * 64 * 3;

  const int B = 2;
  const int NFa[5] = {64, 128, 256, 512, 512};
  const int latStride = 10 * 512;

  // latent rows (JAX clamps OOB static indices): conv0:0, r0:1, u:{1,6,6,6}, c:5, r:6
  auto style = [&](int sid, int row, const float* sw, const float* sb, int Cin) {
    style_kernel<<<dim3(B), 256, 0, stream>>>(latents + row * 512, latStride, sw, sb, Cin, S + sid * 1024);
  };
  style(0, 0, sw0, sb0, 512);
  style(1, 1, swr0, sbr0, 512);
  int cprev0[4] = {512, 128, 256, 512};
  int rowu[4] = {1, 6, 6, 6};
  for (int l = 0; l < 4; l++) {
    int c = NFa[l + 1];
    style(2 + l * 3, rowu[l], swu[l], sbu[l], cprev0[l]);
    style(3 + l * 3, 5, swc[l], sbc[l], c);
    style(4 + l * 3, 6, swr[l], sbr[l], c);
  }

  auto demod = [&](int did, int sid, const float* w, int Cin, int Cout) {
    demod_kernel<<<dim3((Cout + 255) / 256, B), 256, 0, stream>>>(w, S + sid * 1024, 9, Cin, Cout, D + did * 1024);
  };
  demod(0, 0, w0, 512, 512);
  for (int l = 0; l < 4; l++) {
    int c = NFa[l + 1];
    demod(1 + l * 2, 2 + l * 3, wu[l], cprev0[l], c);
    demod(2 + l * 2, 3 + l * 3, wc[l], c, c);
  }

  auto conv = [&](const float* x, size_t xbs, int H, int Cin, int Cout,
                  const float* wp, const float* bp, int sid, int did,
                  const float* noise, const float* ns, float* out, int act) {
    int cs = __builtin_ctz((unsigned)Cin);
    size_t lds = (size_t)18 * Cin * sizeof(float);
    modconv3x3_kernel<<<dim3(H * (H / 4), B), 256, lds, stream>>>(
        x, xbs, H, H, Cin, cs, Cout, wp, bp, S + sid * 1024, D + did * 1024,
        noise, ns, out, act);
  };

  // layer 0: 4x4 modconv(const) + noise + leaky
  conv(cnst, 0, 4, 512, 512, w0, b0, 0, 0, noise0, ns0, bufA, 1);
  rgb_kernel<<<dim3(16, B), 64, 0, stream>>>(bufA, 4, 4, 512, wr0, br0, S + 1024, nullptr, rgbA);

  float* y = bufA; float* yo = bufB;
  float* rgb = rgbA; float* rgbo = rgbB;
  int Hc = 4; int cp = 512;
  for (int l = 0; l < 4; l++) {
    int c = NFa[l + 1];
    int H2 = Hc * 2;
    blur_up_kernel<<<dim3(H2 * H2, B), 256, 0, stream>>>(y, Hc, Hc, cp, yo);
    conv(yo, (size_t)H2 * H2 * cp, H2, cp, c, wu[l], bu[l], 2 + l * 3, 1 + l * 2, nullptr, nullptr, y, 0);
    conv(y, (size_t)H2 * H2 * c, H2, c, c, wc[l], bc[l], 3 + l * 3, 2 + l * 2, nullptr, nullptr, yo, 0);
    { float* t = y; y = yo; yo = t; }
    float* rout = (l == 3) ? (float*)d_out : rgbo;
    rgb_kernel<<<dim3(H2 * H2, B), 64, 0, stream>>>(y, H2, H2, c, wr[l], br_[l], S + (4 + l * 3) * 1024, rgb, rout);
    { float* t = rgb; rgb = rgbo; rgbo = t; }
    Hc = H2; cp = c;
  }
  (void)in_sizes; (void)n_in; (void)out_size; (void)ws_size;
}

// Round 2
// 8135.503 us; speedup vs baseline: 3.5133x; 3.5133x over previous
//
#include <hip/hip_runtime.h>

#define LEAKY(v) ((v) > 0.f ? (v) : 0.01f * (v))

// ---------------- style: s[b,ci] = latent_row[b] @ sw[:,ci] + sb[ci] ----------------
__global__ __launch_bounds__(256) void style_kernel(
    const float* __restrict__ lat, int latStride,
    const float* __restrict__ sw, const float* __restrict__ sb,
    int Cin, float* __restrict__ s_out)
{
  int b = blockIdx.x;
  const float* l = lat + (size_t)b * latStride;
  for (int ci = threadIdx.x; ci < Cin; ci += 256) {
    float acc = sb[ci];
    for (int k = 0; k < 512; k++) acc += l[k] * sw[(size_t)k * Cin + ci];
    s_out[b * 512 + ci] = acc;
  }
}

// ---------------- demod: d[b,co] = rsqrt(sum_{kt,ci} (w*s)^2 + 1e-8) ----------------
// block = 64 couts x 4 row-slices; grid = (ceil(Cout/64), B)
__global__ __launch_bounds__(256) void demod_kernel(
    const float* __restrict__ w, const float* __restrict__ s,
    int KK, int Cin, int Cout, float* __restrict__ d_out)
{
  __shared__ float red[256];
  int b = blockIdx.y;
  int co = blockIdx.x * 64 + (threadIdx.x & 63);
  int slice = threadIdx.x >> 6;
  int cmask = Cin - 1;
  float acc = 0.f;
  if (co < Cout) {
    int R = KK * Cin;
    const float* sv = s + b * 512;
    for (int r = slice; r < R; r += 4) {
      float wv = w[(size_t)r * Cout + co];
      float svv = sv[r & cmask];
      float t = wv * svv;
      acc += t * t;
    }
  }
  red[threadIdx.x] = acc;
  __syncthreads();
  if (threadIdx.x < 64) {
    float a = red[threadIdx.x] + red[threadIdx.x + 64] + red[threadIdx.x + 128] + red[threadIdx.x + 192];
    if (co < Cout) d_out[b * 512 + co] = rsqrtf(a + 1e-8f);
  }
}

// ---------------- blur_up taps: 2x upsample + [1,3,3,1] FIR (separable) ----------------
__device__ inline void blur_taps(int o, int* r0, int* r1, float* w0, float* w1)
{
  if ((o & 1) == 0) { *r0 = (o >> 1) - 1; *w0 = 1.f; *r1 = (o >> 1); *w1 = 3.f; }
  else              { *r0 = (o - 1) >> 1; *w0 = 3.f; *r1 = ((o - 1) >> 1) + 1; *w1 = 1.f; }
}

__global__ __launch_bounds__(256) void blur_up_kernel(
    const float* __restrict__ x, int H, int W, int C, float* __restrict__ out)
{
  int b = blockIdx.y;
  int W2 = W * 2, H2 = H * 2;
  int pix = blockIdx.x;
  int oy = pix / W2, ox = pix % W2;
  int ry0, ry1, rx0, rx1; float wy0, wy1, wx0, wx1;
  blur_taps(oy, &ry0, &ry1, &wy0, &wy1);
  blur_taps(ox, &rx0, &rx1, &wx0, &wx1);
  bool vy0 = (ry0 >= 0 && ry0 < H), vy1 = (ry1 >= 0 && ry1 < H);
  bool vx0 = (rx0 >= 0 && rx0 < W), vx1 = (rx1 >= 0 && rx1 < W);
  const float* base = x + (size_t)b * H * W * C;
  float* ob = out + (((size_t)b * H2 + oy) * W2 + ox) * C;
  for (int c = threadIdx.x; c < C; c += 256) {
    float acc = 0.f;
    if (vy0) {
      const float* r = base + (size_t)(ry0 * W) * C;
      if (vx0) acc += wy0 * wx0 * r[(size_t)rx0 * C + c];
      if (vx1) acc += wy0 * wx1 * r[(size_t)rx1 * C + c];
    }
    if (vy1) {
      const float* r = base + (size_t)(ry1 * W) * C;
      if (vx0) acc += wy1 * wx0 * r[(size_t)rx0 * C + c];
      if (vx1) acc += wy1 * wx1 * r[(size_t)rx1 * C + c];
    }
    ob[c] = acc * (1.f / 16.f);
  }
}

// ---------------- 3x3 modulated conv (SAME). Block: PIX pixels x (<=512 couts) ----------------
// No address-taken locals anywhere: accumulators stay in VGPRs.
template<int PIX>
__global__ __launch_bounds__(256) void modconv3x3_kernel(
    const float* __restrict__ x, size_t xBStride, int H, int W, int Cin, int cinShift, int Cout,
    const float* __restrict__ w, const float* __restrict__ bias,
    const float* __restrict__ s, const float* __restrict__ dmod,
    const float* __restrict__ noise, const float* __restrict__ ns,
    float* __restrict__ out, int doAct)
{
  extern __shared__ float lds[];
  const int COLS = PIX + 2;
  const int tid = threadIdx.x;
  const int b = blockIdx.y;
  const int wb = W / PIX;
  const int row = blockIdx.x / wb;
  const int x0 = (blockIdx.x % wb) * PIX;

  const float* xb = x + (size_t)b * xBStride;
  const float* sv = s + b * 512;

  // stage 3 rows x COLS cols x Cin patch, style folded in
  const int tot = 3 * COLS << cinShift;
  for (int idx = tid; idx < tot; idx += 256) {
    int ci = idx & (Cin - 1);
    int t = idx >> cinShift;
    int col = t % COLS;
    int ry = t / COLS;
    int gy = row + ry - 1;
    int gx = x0 + col - 1;
    float v = 0.f;
    if (gy >= 0 && gy < H && gx >= 0 && gx < W)
      v = xb[((size_t)(gy * W + gx) << cinShift) + ci] * sv[ci];
    lds[idx] = v;
  }
  __syncthreads();

  float acc0[PIX];
  float acc1[PIX];
#pragma unroll
  for (int p = 0; p < PIX; p++) { acc0[p] = 0.f; acc1[p] = 0.f; }
  const int co0 = tid;
  const int co1 = tid + 256;
  const bool a0 = co0 < Cout;
  const bool a1 = co1 < Cout;

  const float4* ldsv = (const float4*)lds;
  const int cin4Shift = cinShift - 2;

  for (int kt = 0; kt < 9; kt++) {
    int ky = kt / 3, kx = kt % 3;
    const float* wr = w + ((size_t)(kt << cinShift)) * Cout + co0;
    for (int c4 = 0; c4 < (Cin >> 2); c4++) {
      float wA0 = 0.f, wA1 = 0.f, wA2 = 0.f, wA3 = 0.f;
      float wB0 = 0.f, wB1 = 0.f, wB2 = 0.f, wB3 = 0.f;
      if (a0) { wA0 = wr[0]; }
      if (a1) { wB0 = wr[256]; }
      wr += Cout;
      if (a0) { wA1 = wr[0]; }
      if (a1) { wB1 = wr[256]; }
      wr += Cout;
      if (a0) { wA2 = wr[0]; }
      if (a1) { wB2 = wr[256]; }
      wr += Cout;
      if (a0) { wA3 = wr[0]; }
      if (a1) { wB3 = wr[256]; }
      wr += Cout;
#pragma unroll
      for (int p = 0; p < PIX; p++) {
        float4 v = ldsv[((ky * COLS + kx + p) << cin4Shift) + c4];
        acc0[p] += v.x * wA0;
        acc0[p] += v.y * wA1;
        acc0[p] += v.z * wA2;
        acc0[p] += v.w * wA3;
        acc1[p] += v.x * wB0;
        acc1[p] += v.y * wB1;
        acc1[p] += v.z * wB2;
        acc1[p] += v.w * wB3;
      }
    }
  }

  float dm0 = 1.f, dm1 = 1.f;
  if (dmod) {
    if (a0) dm0 = dmod[b * 512 + co0];
    if (a1) dm1 = dmod[b * 512 + co1];
  }
  float bv0 = a0 ? bias[co0] : 0.f;
  float bv1 = a1 ? bias[co1] : 0.f;
  float* ob = out + ((size_t)((b * H + row) * W) + x0) * Cout;
#pragma unroll
  for (int p = 0; p < PIX; p++) {
    float nz = 0.f;
    if (noise) nz = ns[0] * noise[b * (H * W) + row * W + (x0 + p)];
    if (a0) {
      float v = acc0[p] * dm0 + bv0 + nz;
      if (doAct) v = LEAKY(v);
      ob[(size_t)p * Cout + co0] = v;
    }
    if (a1) {
      float v = acc1[p] * dm1 + bv1 + nz;
      if (doAct) v = LEAKY(v);
      ob[(size_t)p * Cout + co1] = v;
    }
  }
}

// ---------------- to_rgb: 1x1 modconv (no demod) + leaky + optional blur-up skip add ----------------
__global__ __launch_bounds__(64) void rgb_kernel(
    const float* __restrict__ y, int H, int W, int Cin,
    const float* __restrict__ w, const float* __restrict__ bias,
    const float* __restrict__ s, const float* __restrict__ prev,
    float* __restrict__ out)
{
  int b = blockIdx.y;
  int pix = blockIdx.x;
  int oy = pix / W, ox = pix % W;
  const float* xp = y + (((size_t)b * H + oy) * W + ox) * Cin;
  const float* sv = s + b * 512;
  float p0 = 0.f, p1 = 0.f, p2 = 0.f;
  for (int ci = threadIdx.x; ci < Cin; ci += 64) {
    float v = xp[ci] * sv[ci];
    p0 += v * w[ci * 3 + 0];
    p1 += v * w[ci * 3 + 1];
    p2 += v * w[ci * 3 + 2];
  }
  for (int off = 32; off > 0; off >>= 1) {
    p0 += __shfl_down(p0, off);
    p1 += __shfl_down(p1, off);
    p2 += __shfl_down(p2, off);
  }
  if (threadIdx.x == 0) {
    float r0 = p0 + bias[0], r1 = p1 + bias[1], r2 = p2 + bias[2];
    float sk0 = 0.f, sk1 = 0.f, sk2 = 0.f;
    if (prev) {
      int Hp = H >> 1, Wp = W >> 1;
      int ry0, ry1, rx0, rx1; float wy0, wy1, wx0, wx1;
      blur_taps(oy, &ry0, &ry1, &wy0, &wy1);
      blur_taps(ox, &rx0, &rx1, &wx0, &wx1);
      bool vy0 = (ry0 >= 0 && ry0 < Hp), vy1 = (ry1 >= 0 && ry1 < Hp);
      bool vx0 = (rx0 >= 0 && rx0 < Wp), vx1 = (rx1 >= 0 && rx1 < Wp);
      const float* base = prev + (size_t)b * Hp * Wp * 3;
      float acc0 = 0.f, acc1 = 0.f, acc2 = 0.f;
      if (vy0 && vx0) {
        const float* q = base + (size_t)(ry0 * Wp + rx0) * 3;
        float wgt = wy0 * wx0; acc0 += wgt * q[0]; acc1 += wgt * q[1]; acc2 += wgt * q[2];
      }
      if (vy0 && vx1) {
        const float* q = base + (size_t)(ry0 * Wp + rx1) * 3;
        float wgt = wy0 * wx1; acc0 += wgt * q[0]; acc1 += wgt * q[1]; acc2 += wgt * q[2];
      }
      if (vy1 && vx0) {
        const float* q = base + (size_t)(ry1 * Wp + rx0) * 3;
        float wgt = wy1 * wx0; acc0 += wgt * q[0]; acc1 += wgt * q[1]; acc2 += wgt * q[2];
      }
      if (vy1 && vx1) {
        const float* q = base + (size_t)(ry1 * Wp + rx1) * 3;
        float wgt = wy1 * wx1; acc0 += wgt * q[0]; acc1 += wgt * q[1]; acc2 += wgt * q[2];
      }
      sk0 = acc0 * (1.f / 16.f); sk1 = acc1 * (1.f / 16.f); sk2 = acc2 * (1.f / 16.f);
    }
    float* ob = out + (((size_t)b * H + oy) * W + ox) * 3;
    ob[0] = LEAKY(r0) + sk0;
    ob[1] = LEAKY(r1) + sk1;
    ob[2] = LEAKY(r2) + sk2;
  }
}

extern "C" void kernel_launch(void* const* d_in, const int* in_sizes, int n_in,
                              void* d_out, int out_size, void* d_ws, size_t ws_size,
                              hipStream_t stream)
{
  auto F = [&](int k) { return (const float*)d_in[k]; };
  const float* latents = F(0);
  const float* cnst = F(1);
  const float* w0 = F(2);  const float* b0 = F(3);  const float* sw0 = F(4);  const float* sb0 = F(5);
  const float* ns0 = F(6); const float* noise0 = F(7);
  const float* wr0 = F(8); const float* br0 = F(9); const float* swr0 = F(10); const float* sbr0 = F(11);
  const float *wu[4], *bu[4], *swu[4], *sbu[4];
  const float *wc[4], *bc[4], *swc[4], *sbc[4];
  const float *wr[4], *br_[4], *swr[4], *sbr[4];
  int k = 12;
  for (int l = 0; l < 4; l++) {
    wu[l] = F(k++); bu[l] = F(k++); swu[l] = F(k++); sbu[l] = F(k++);
    wc[l] = F(k++); bc[l] = F(k++); swc[l] = F(k++); sbc[l] = F(k++);
    wr[l] = F(k++); br_[l] = F(k++); swr[l] = F(k++); sbr[l] = F(k++);
  }

  float* ws = (float*)d_ws;
  float* S = ws;                          // 14 convs * (2*512)
  float* D = S + 14 * 1024;               // 9 demod convs * (2*512)
  float* bufA = D + 9 * 1024;             // 2*64*64*512 floats
  float* bufB = bufA + 2 * 64 * 64 * 512;
  float* rgbA = bufB + 2 * 64 * 64 * 512; // 2*64*64*3
  float* rgbB = rgbA + 2 * 64 * 64 * 3;

  const int B = 2;
  const int NFa[5] = {64, 128, 256, 512, 512};
  const int latStride = 10 * 512;

  // latent rows (JAX clamps OOB static indices): conv0:0, r0:1, u:{1,6,6,6}, c:5, r:6
  auto style = [&](int sid, int row, const float* sw, const float* sb, int Cin) {
    style_kernel<<<dim3(B), 256, 0, stream>>>(latents + row * 512, latStride, sw, sb, Cin, S + sid * 1024);
  };
  style(0, 0, sw0, sb0, 512);
  style(1, 1, swr0, sbr0, 512);
  int cprev0[4] = {512, 128, 256, 512};
  int rowu[4] = {1, 6, 6, 6};
  for (int l = 0; l < 4; l++) {
    int c = NFa[l + 1];
    style(2 + l * 3, rowu[l], swu[l], sbu[l], cprev0[l]);
    style(3 + l * 3, 5, swc[l], sbc[l], c);
    style(4 + l * 3, 6, swr[l], sbr[l], c);
  }

  auto demod = [&](int did, int sid, const float* w, int Cin, int Cout) {
    demod_kernel<<<dim3((Cout + 63) / 64, B), 256, 0, stream>>>(w, S + sid * 1024, 9, Cin, Cout, D + did * 1024);
  };
  demod(0, 0, w0, 512, 512);
  for (int l = 0; l < 4; l++) {
    int c = NFa[l + 1];
    demod(1 + l * 2, 2 + l * 3, wu[l], cprev0[l], c);
    demod(2 + l * 2, 3 + l * 3, wc[l], c, c);
  }

  auto conv = [&](const float* x, size_t xbs, int H, int Cin, int Cout,
                  const float* wp, const float* bp, int sid, int did,
                  const float* noise, const float* ns, float* out, int act) {
    int cs = __builtin_ctz((unsigned)Cin);
    if (H >= 8) {
      size_t lds = (size_t)3 * 10 * Cin * sizeof(float);
      modconv3x3_kernel<8><<<dim3(H * (H / 8), B), 256, lds, stream>>>(
          x, xbs, H, H, Cin, cs, Cout, wp, bp, S + sid * 1024, D + did * 1024,
          noise, ns, out, act);
    } else {
      size_t lds = (size_t)3 * 6 * Cin * sizeof(float);
      modconv3x3_kernel<4><<<dim3(H * (H / 4), B), 256, lds, stream>>>(
          x, xbs, H, H, Cin, cs, Cout, wp, bp, S + sid * 1024, D + did * 1024,
          noise, ns, out, act);
    }
  };

  // layer 0: 4x4 modconv(const) + noise + leaky
  conv(cnst, 0, 4, 512, 512, w0, b0, 0, 0, noise0, ns0, bufA, 1);
  rgb_kernel<<<dim3(16, B), 64, 0, stream>>>(bufA, 4, 4, 512, wr0, br0, S + 1024, nullptr, rgbA);

  float* y = bufA; float* yo = bufB;
  float* rgb = rgbA; float* rgbo = rgbB;
  int Hc = 4; int cp = 512;
  for (int l = 0; l < 4; l++) {
    int c = NFa[l + 1];
    int H2 = Hc * 2;
    blur_up_kernel<<<dim3(H2 * H2, B), 256, 0, stream>>>(y, Hc, Hc, cp, yo);
    conv(yo, (size_t)H2 * H2 * cp, H2, cp, c, wu[l], bu[l], 2 + l * 3, 1 + l * 2, nullptr, nullptr, y, 0);
    conv(y, (size_t)H2 * H2 * c, H2, c, c, wc[l], bc[l], 3 + l * 3, 2 + l * 2, nullptr, nullptr, yo, 0);
    { float* t = y; y = yo; yo = t; }
    float* rout = (l == 3) ? (float*)d_out : rgbo;
    rgb_kernel<<<dim3(H2 * H2, B), 64, 0, stream>>>(y, H2, H2, c, wr[l], br_[l], S + (4 + l * 3) * 1024, rgb, rout);
    { float* t = rgb; rgb = rgbo; rgbo = t; }
    Hc = H2; cp = c;
  }
  (void)in_sizes; (void)n_in; (void)out_size; (void)ws_size;
}

// Round 3
// 2226.683 us; speedup vs baseline: 12.8365x; 3.6536x over previous
//
#include <hip/hip_runtime.h>

#define LEAKY(v) ((v) > 0.f ? (v) : 0.01f * (v))

typedef __attribute__((ext_vector_type(8))) short bf16x8;
typedef __attribute__((ext_vector_type(4))) float floatx4;

__device__ inline unsigned short f2bf(float f) {
  unsigned u = __float_as_uint(f);
  unsigned r = u + 0x7FFFu + ((u >> 16) & 1u);
  return (unsigned short)(r >> 16);
}

// ---------------- fused style: all 14 affines in one dispatch ----------------
struct StyleDesc { const float* sw; const float* sb; int row; int cin; };
struct StyleArgs { StyleDesc d[14]; };

__global__ __launch_bounds__(256) void style_all_kernel(
    const float* __restrict__ lat, StyleArgs A, float* __restrict__ S)
{
  int bid = blockIdx.x;
  int chunk = bid & 1, b = (bid >> 1) & 1, sid = bid >> 2;
  StyleDesc d = A.d[sid];
  int ci = chunk * 256 + threadIdx.x;
  if (ci >= d.cin) return;
  const float* l = lat + (size_t)b * (10 * 512) + d.row * 512;
  float acc = d.sb[ci];
  for (int k = 0; k < 512; k += 4) {
    acc += l[k] * d.sw[(size_t)k * d.cin + ci];
    acc += l[k + 1] * d.sw[(size_t)(k + 1) * d.cin + ci];
    acc += l[k + 2] * d.sw[(size_t)(k + 2) * d.cin + ci];
    acc += l[k + 3] * d.sw[(size_t)(k + 3) * d.cin + ci];
  }
  S[sid * 1024 + b * 512 + ci] = acc;
}

// ---------------- fused demod: all 9 in one dispatch ----------------
struct DemodDesc { const float* w; int sid; int did; int cin; int cout; int start; };
struct DemodArgs { DemodDesc d[9]; };

__global__ __launch_bounds__(256) void demod_all_kernel(
    DemodArgs A, const float* __restrict__ S, float* __restrict__ Dout)
{
  __shared__ float red[256];
  int bid = blockIdx.x;
  int c = 0;
  while (c < 8 && bid >= A.d[c + 1].start) c++;
  DemodDesc d = A.d[c];
  int rel = bid - d.start;
  int chunksPerB = d.cout >> 6;
  int b = rel / chunksPerB;
  int coc = rel - b * chunksPerB;
  int co = coc * 64 + (threadIdx.x & 63);
  int slice = threadIdx.x >> 6;
  const float* sv = S + d.sid * 1024 + b * 512;
  int R = 9 * d.cin, cmask = d.cin - 1;
  float acc = 0.f;
  for (int r = slice; r < R; r += 4) {
    float wv = d.w[(size_t)r * d.cout + co];
    float s = sv[r & cmask];
    float t = wv * s;
    acc += t * t;
  }
  red[threadIdx.x] = acc;
  __syncthreads();
  if (threadIdx.x < 64) {
    float a = red[threadIdx.x] + red[threadIdx.x + 64] + red[threadIdx.x + 128] + red[threadIdx.x + 192];
    Dout[d.did * 1024 + b * 512 + co] = rsqrtf(a + 1e-8f);
  }
}

// ---------------- fused weight prep: fp32 [kt][ci][co] -> bf16 [co][k'] ----------------
// k' = (ci>>5)*288 + kt*32 + (ci&31)  (32-ci groups contiguous per kt for frag loads)
struct WPD { const float* src; unsigned short* dst; int cin; int cout; int start; };
struct WPArgs { WPD d[6]; int total; };

__global__ __launch_bounds__(256) void wprep_kernel(WPArgs A)
{
  int chunk = blockIdx.x * 256 + threadIdx.x;
  if (chunk >= A.total) return;
  int c = 0;
  while (c < 5 && chunk >= A.d[c + 1].start) c++;
  WPD d = A.d[c];
  int rel = chunk - d.start;
  int cpc = d.cin * 9 / 8;
  int co = rel / cpc;
  int k0 = (rel - co * cpc) * 8;
  int cig = k0 / 288;
  int r = k0 - cig * 288;
  int kt = r >> 5;
  int cibase = cig * 32 + (r & 31);
  const float* sp = d.src + (size_t)(kt * d.cin + cibase) * d.cout + co;
  size_t st = d.cout;
  unsigned r0 = f2bf(sp[0]) | ((unsigned)f2bf(sp[st]) << 16);
  unsigned r1 = f2bf(sp[2 * st]) | ((unsigned)f2bf(sp[3 * st]) << 16);
  unsigned r2 = f2bf(sp[4 * st]) | ((unsigned)f2bf(sp[5 * st]) << 16);
  unsigned r3 = f2bf(sp[6 * st]) | ((unsigned)f2bf(sp[7 * st]) << 16);
  uint4 v = {r0, r1, r2, r3};
  *(uint4*)(d.dst + (size_t)co * (d.cin * 9) + k0) = v;
}

// ---------------- blur_up taps ----------------
__device__ inline void blur_taps(int o, int* r0, int* r1, float* w0, float* w1)
{
  if ((o & 1) == 0) { *r0 = (o >> 1) - 1; *w0 = 1.f; *r1 = (o >> 1); *w1 = 3.f; }
  else              { *r0 = (o - 1) >> 1; *w0 = 3.f; *r1 = ((o - 1) >> 1) + 1; *w1 = 1.f; }
}

__global__ __launch_bounds__(256) void blur_up_kernel(
    const float* __restrict__ x, int H, int W, int C, float* __restrict__ out)
{
  int b = blockIdx.y;
  int W2 = W * 2;
  int pix = blockIdx.x;
  int oy = pix / W2, ox = pix % W2;
  int ry0, ry1, rx0, rx1; float wy0, wy1, wx0, wx1;
  blur_taps(oy, &ry0, &ry1, &wy0, &wy1);
  blur_taps(ox, &rx0, &rx1, &wx0, &wx1);
  bool vy0 = (ry0 >= 0 && ry0 < H), vy1 = (ry1 >= 0 && ry1 < H);
  bool vx0 = (rx0 >= 0 && rx0 < W), vx1 = (rx1 >= 0 && rx1 < W);
  const float* base = x + (size_t)b * H * W * C;
  float* ob = out + (((size_t)b * W2 + oy) * W2 + ox) * C;
  for (int c = threadIdx.x; c < C; c += 256) {
    float acc = 0.f;
    if (vy0) {
      const float* r = base + (size_t)(ry0 * W) * C;
      if (vx0) acc += wy0 * wx0 * r[(size_t)rx0 * C + c];
      if (vx1) acc += wy0 * wx1 * r[(size_t)rx1 * C + c];
    }
    if (vy1) {
      const float* r = base + (size_t)(ry1 * W) * C;
      if (vx0) acc += wy1 * wx0 * r[(size_t)rx0 * C + c];
      if (vx1) acc += wy1 * wx1 * r[(size_t)rx1 * C + c];
    }
    ob[c] = acc * (1.f / 16.f);
  }
}

// ---------------- prep_up: blur_up + style fold + bf16 cast ----------------
__global__ __launch_bounds__(256) void prep_up_kernel(
    const float* __restrict__ y, int Hc, int C,
    const float* __restrict__ s, unsigned short* __restrict__ out)
{
  int b = blockIdx.y;
  int W2 = Hc * 2;
  int pix = blockIdx.x;
  int oy = pix / W2, ox = pix - oy * W2;
  int ry0, ry1, rx0, rx1; float wy0, wy1, wx0, wx1;
  blur_taps(oy, &ry0, &ry1, &wy0, &wy1);
  blur_taps(ox, &rx0, &rx1, &wx0, &wx1);
  bool vy0 = (ry0 >= 0 && ry0 < Hc), vy1 = (ry1 >= 0 && ry1 < Hc);
  bool vx0 = (rx0 >= 0 && rx0 < Hc), vx1 = (rx1 >= 0 && rx1 < Hc);
  const float* base = y + (size_t)b * Hc * Hc * C;
  unsigned short* ob = out + (((size_t)b * W2 + oy) * W2 + ox) * C;
  const float* sv = s + b * 512;
  for (int c = threadIdx.x; c < C; c += 256) {
    float acc = 0.f;
    if (vy0) {
      const float* r = base + (size_t)(ry0 * Hc) * C;
      if (vx0) acc += wy0 * wx0 * r[(size_t)rx0 * C + c];
      if (vx1) acc += wy0 * wx1 * r[(size_t)rx1 * C + c];
    }
    if (vy1) {
      const float* r = base + (size_t)(ry1 * Hc) * C;
      if (vx0) acc += wy1 * wx0 * r[(size_t)rx0 * C + c];
      if (vx1) acc += wy1 * wx1 * r[(size_t)rx1 * C + c];
    }
    ob[c] = f2bf(acc * (1.f / 16.f) * sv[c]);
  }
}

// ---------------- MFMA implicit-GEMM 3x3 conv ----------------
// Block: 128 pixels (M) x 64 couts (N); 4 waves stacked in M (32 pixels each).
// Wave: 2 m-frags x 4 n-frags of v_mfma_f32_16x16x32_bf16.
// xp: bf16 [b][H][W][Cin] (style folded).  wT: bf16 [Cout][9*Cin] reordered.
// Epilogue: *dmod + bias, then write fp32 (c-convs) or bf16*(next style) (u-convs).
__global__ __launch_bounds__(256) void mfma_conv_kernel(
    const unsigned short* __restrict__ xp, int H, int WLOG, int Cin, int Cout,
    const unsigned short* __restrict__ wT,
    const float* __restrict__ bias, const float* __restrict__ dmod,
    float* __restrict__ outF, unsigned short* __restrict__ outBf,
    const float* __restrict__ sNext)
{
  extern __shared__ unsigned short sm[];
  const int W = 1 << WLOG;
  const int Rt = 128 >> WLOG;           // tile rows
  const int PR = Rt + 2, PC = W + 2;
  const int patchU = PR * PC * 40;      // ushort; 40/pixel (32 ci + pad) for bank spread
  unsigned short* Bw = sm + patchU;     // 64 rows x 296 ushort (592B, 16B-aligned rows)

  const int tid = threadIdx.x;
  const int wave = tid >> 6;
  const int lane = tid & 63;
  const int q = lane >> 4;
  const int l15 = lane & 15;

  const int HW = H << WLOG;
  const int m0 = blockIdx.x << 7;
  const int b = m0 / HW;
  const int y0 = (m0 - b * HW) >> WLOG;
  const int co0 = blockIdx.y << 6;
  const int Kp = Cin * 9;
  const unsigned short* xb = xp + (size_t)b * HW * Cin;

  // hoisted patch-staging slots (PR*PC*4 <= 1280 -> 5 iters)
  const int pSlots = PR * PC * 4;
  int pLds[5], pSrc[5];
#pragma unroll
  for (int i = 0; i < 5; i++) {
    int sidx = tid + i * 256;
    pLds[i] = -1; pSrc[i] = -1;
    if (sidx < pSlots) {
      int pidx = sidx >> 2, part = sidx & 3;
      int pr = pidx / PC, pc = pidx - pr * PC;
      int gy = y0 + pr - 1, gx = pc - 1;
      pLds[i] = pidx * 40 + part * 8;
      if ((unsigned)gy < (unsigned)H && (unsigned)gx < (unsigned)W)
        pSrc[i] = ((gy << WLOG) + gx) * Cin + part * 8;
    }
  }
  // hoisted B-staging slots (64*36 = 2304 = 9*256 exactly)
  int bLds[9], bSrc[9];
#pragma unroll
  for (int i = 0; i < 9; i++) {
    int sidx = tid + i * 256;
    int n = sidx / 36, c16 = sidx - n * 36;
    bLds[i] = n * 296 + c16 * 8;
    bSrc[i] = (co0 + n) * Kp + c16 * 8;
  }

  floatx4 zero = {0.f, 0.f, 0.f, 0.f};
  floatx4 acc[2][4];
#pragma unroll
  for (int mi = 0; mi < 2; mi++)
#pragma unroll
    for (int s = 0; s < 4; s++) acc[mi][s] = zero;

  const int mA0 = wave * 32 + l15;
  const int mA1 = mA0 + 16;
  const int aBase0 = ((mA0 >> WLOG) * PC + (mA0 & (W - 1))) * 40 + q * 8;
  const int aBase1 = ((mA1 >> WLOG) * PC + (mA1 & (W - 1))) * 40 + q * 8;
  const int bBase = l15 * 296 + q * 8;

  const int nGroups = Cin >> 5;
  for (int g = 0; g < nGroups; g++) {
    __syncthreads();
    {
      const int gci = g << 5;
#pragma unroll
      for (int i = 0; i < 5; i++) {
        if (pLds[i] >= 0) {
          uint4 v = {0u, 0u, 0u, 0u};
          if (pSrc[i] >= 0) v = *(const uint4*)(xb + pSrc[i] + gci);
          *(uint4*)(sm + pLds[i]) = v;
        }
      }
      const int gw = g * 288;
#pragma unroll
      for (int i = 0; i < 9; i++)
        *(uint4*)(Bw + bLds[i]) = *(const uint4*)(wT + bSrc[i] + gw);
    }
    __syncthreads();
#pragma unroll
    for (int kt = 0; kt < 9; kt++) {
      const int ky = kt / 3, kx = kt - (kt / 3) * 3;
      const int ao = (ky * PC + kx) * 40;
      bf16x8 a0 = *(const bf16x8*)(sm + aBase0 + ao);
      bf16x8 a1 = *(const bf16x8*)(sm + aBase1 + ao);
      const int bo = bBase + kt * 32;
#pragma unroll
      for (int s = 0; s < 4; s++) {
        bf16x8 bb = *(const bf16x8*)(Bw + bo + s * (16 * 296));
        acc[0][s] = __builtin_amdgcn_mfma_f32_16x16x32_bf16(a0, bb, acc[0][s], 0, 0, 0);
        acc[1][s] = __builtin_amdgcn_mfma_f32_16x16x32_bf16(a1, bb, acc[1][s], 0, 0, 0);
      }
    }
  }

  // epilogue: C/D layout col=lane&15, row=(lane>>4)*4+reg  [m89-verified]
#pragma unroll
  for (int s = 0; s < 4; s++) {
    const int co = co0 + s * 16 + l15;
    const float dm = dmod[b * 512 + co];
    const float bv = bias[co];
    const float sn = sNext ? sNext[b * 512 + co] : 0.f;
#pragma unroll
    for (int mi = 0; mi < 2; mi++) {
#pragma unroll
      for (int r = 0; r < 4; r++) {
        const int mloc = wave * 32 + mi * 16 + q * 4 + r;
        const int py = y0 + (mloc >> WLOG);
        const int px = mloc & (W - 1);
        const size_t oidx = (((size_t)b * H + py) * W + px) * Cout + co;
        const float v = acc[mi][s][r] * dm + bv;
        if (outF) outF[oidx] = v;
        if (outBf) outBf[oidx] = f2bf(v * sn);
      }
    }
  }
}

// ---------------- fp32 3x3 modulated conv (kept for 4x4 / 8x8 layers) ----------------
template<int PIX>
__global__ __launch_bounds__(256) void modconv3x3_kernel(
    const float* __restrict__ x, size_t xBStride, int H, int W, int Cin, int cinShift, int Cout,
    const float* __restrict__ w, const float* __restrict__ bias,
    const float* __restrict__ s, const float* __restrict__ dmod,
    const float* __restrict__ noise, const float* __restrict__ ns,
    float* __restrict__ out, int doAct)
{
  extern __shared__ float lds[];
  const int COLS = PIX + 2;
  const int tid = threadIdx.x;
  const int b = blockIdx.y;
  const int wb = W / PIX;
  const int row = blockIdx.x / wb;
  const int x0 = (blockIdx.x % wb) * PIX;

  const float* xb = x + (size_t)b * xBStride;
  const float* sv = s + b * 512;

  const int tot = 3 * COLS << cinShift;
  for (int idx = tid; idx < tot; idx += 256) {
    int ci = idx & (Cin - 1);
    int t = idx >> cinShift;
    int col = t % COLS;
    int ry = t / COLS;
    int gy = row + ry - 1;
    int gx = x0 + col - 1;
    float v = 0.f;
    if (gy >= 0 && gy < H && gx >= 0 && gx < W)
      v = xb[((size_t)(gy * W + gx) << cinShift) + ci] * sv[ci];
    lds[idx] = v;
  }
  __syncthreads();

  float acc0[PIX];
  float acc1[PIX];
#pragma unroll
  for (int p = 0; p < PIX; p++) { acc0[p] = 0.f; acc1[p] = 0.f; }
  const int co0 = tid;
  const int co1 = tid + 256;
  const bool a0 = co0 < Cout;
  const bool a1 = co1 < Cout;

  const float4* ldsv = (const float4*)lds;
  const int cin4Shift = cinShift - 2;

  for (int kt = 0; kt < 9; kt++) {
    int ky = kt / 3, kx = kt % 3;
    const float* wr = w + ((size_t)(kt << cinShift)) * Cout + co0;
    for (int c4 = 0; c4 < (Cin >> 2); c4++) {
      float wA0 = 0.f, wA1 = 0.f, wA2 = 0.f, wA3 = 0.f;
      float wB0 = 0.f, wB1 = 0.f, wB2 = 0.f, wB3 = 0.f;
      if (a0) { wA0 = wr[0]; }
      if (a1) { wB0 = wr[256]; }
      wr += Cout;
      if (a0) { wA1 = wr[0]; }
      if (a1) { wB1 = wr[256]; }
      wr += Cout;
      if (a0) { wA2 = wr[0]; }
      if (a1) { wB2 = wr[256]; }
      wr += Cout;
      if (a0) { wA3 = wr[0]; }
      if (a1) { wB3 = wr[256]; }
      wr += Cout;
#pragma unroll
      for (int p = 0; p < PIX; p++) {
        float4 v = ldsv[((ky * COLS + kx + p) << cin4Shift) + c4];
        acc0[p] += v.x * wA0; acc0[p] += v.y * wA1; acc0[p] += v.z * wA2; acc0[p] += v.w * wA3;
        acc1[p] += v.x * wB0; acc1[p] += v.y * wB1; acc1[p] += v.z * wB2; acc1[p] += v.w * wB3;
      }
    }
  }

  float dm0 = 1.f, dm1 = 1.f;
  if (dmod) {
    if (a0) dm0 = dmod[b * 512 + co0];
    if (a1) dm1 = dmod[b * 512 + co1];
  }
  float bv0 = a0 ? bias[co0] : 0.f;
  float bv1 = a1 ? bias[co1] : 0.f;
  float* ob = out + ((size_t)((b * H + row) * W) + x0) * Cout;
#pragma unroll
  for (int p = 0; p < PIX; p++) {
    float nz = 0.f;
    if (noise) nz = ns[0] * noise[b * (H * W) + row * W + (x0 + p)];
    if (a0) {
      float v = acc0[p] * dm0 + bv0 + nz;
      if (doAct) v = LEAKY(v);
      ob[(size_t)p * Cout + co0] = v;
    }
    if (a1) {
      float v = acc1[p] * dm1 + bv1 + nz;
      if (doAct) v = LEAKY(v);
      ob[(size_t)p * Cout + co1] = v;
    }
  }
}

// ---------------- to_rgb: 1x1 modconv (no demod) + leaky + blur-up skip add ----------------
__global__ __launch_bounds__(64) void rgb_kernel(
    const float* __restrict__ y, int H, int W, int Cin,
    const float* __restrict__ w, const float* __restrict__ bias,
    const float* __restrict__ s, const float* __restrict__ prev,
    float* __restrict__ out)
{
  int b = blockIdx.y;
  int pix = blockIdx.x;
  int oy = pix / W, ox = pix % W;
  const float* xp = y + (((size_t)b * H + oy) * W + ox) * Cin;
  const float* sv = s + b * 512;
  float p0 = 0.f, p1 = 0.f, p2 = 0.f;
  for (int ci = threadIdx.x; ci < Cin; ci += 64) {
    float v = xp[ci] * sv[ci];
    p0 += v * w[ci * 3 + 0];
    p1 += v * w[ci * 3 + 1];
    p2 += v * w[ci * 3 + 2];
  }
  for (int off = 32; off > 0; off >>= 1) {
    p0 += __shfl_down(p0, off);
    p1 += __shfl_down(p1, off);
    p2 += __shfl_down(p2, off);
  }
  if (threadIdx.x == 0) {
    float r0 = p0 + bias[0], r1 = p1 + bias[1], r2 = p2 + bias[2];
    float sk0 = 0.f, sk1 = 0.f, sk2 = 0.f;
    if (prev) {
      int Hp = H >> 1, Wp = W >> 1;
      int ry0, ry1, rx0, rx1; float wy0, wy1, wx0, wx1;
      blur_taps(oy, &ry0, &ry1, &wy0, &wy1);
      blur_taps(ox, &rx0, &rx1, &wx0, &wx1);
      bool vy0 = (ry0 >= 0 && ry0 < Hp), vy1 = (ry1 >= 0 && ry1 < Hp);
      bool vx0 = (rx0 >= 0 && rx0 < Wp), vx1 = (rx1 >= 0 && rx1 < Wp);
      const float* base = prev + (size_t)b * Hp * Wp * 3;
      float a0 = 0.f, a1 = 0.f, a2 = 0.f;
      if (vy0 && vx0) { const float* qq = base + (size_t)(ry0 * Wp + rx0) * 3; float wg = wy0 * wx0; a0 += wg * qq[0]; a1 += wg * qq[1]; a2 += wg * qq[2]; }
      if (vy0 && vx1) { const float* qq = base + (size_t)(ry0 * Wp + rx1) * 3; float wg = wy0 * wx1; a0 += wg * qq[0]; a1 += wg * qq[1]; a2 += wg * qq[2]; }
      if (vy1 && vx0) { const float* qq = base + (size_t)(ry1 * Wp + rx0) * 3; float wg = wy1 * wx0; a0 += wg * qq[0]; a1 += wg * qq[1]; a2 += wg * qq[2]; }
      if (vy1 && vx1) { const float* qq = base + (size_t)(ry1 * Wp + rx1) * 3; float wg = wy1 * wx1; a0 += wg * qq[0]; a1 += wg * qq[1]; a2 += wg * qq[2]; }
      sk0 = a0 * (1.f / 16.f); sk1 = a1 * (1.f / 16.f); sk2 = a2 * (1.f / 16.f);
    }
    float* ob = out + (((size_t)b * H + oy) * W + ox) * 3;
    ob[0] = LEAKY(r0) + sk0;
    ob[1] = LEAKY(r1) + sk1;
    ob[2] = LEAKY(r2) + sk2;
  }
}

extern "C" void kernel_launch(void* const* d_in, const int* in_sizes, int n_in,
                              void* d_out, int out_size, void* d_ws, size_t ws_size,
                              hipStream_t stream)
{
  auto F = [&](int k) { return (const float*)d_in[k]; };
  const float* latents = F(0);
  const float* cnst = F(1);
  const float* w0 = F(2);  const float* b0 = F(3);  const float* sw0 = F(4);  const float* sb0 = F(5);
  const float* ns0 = F(6); const float* noise0 = F(7);
  const float* wr0 = F(8); const float* br0 = F(9); const float* swr0 = F(10); const float* sbr0 = F(11);
  const float *wu[4], *bu[4], *swu[4], *sbu[4];
  const float *wc[4], *bc[4], *swc[4], *sbc[4];
  const float *wr[4], *br_[4], *swr[4], *sbr[4];
  int k = 12;
  for (int l = 0; l < 4; l++) {
    wu[l] = F(k++); bu[l] = F(k++); swu[l] = F(k++); sbu[l] = F(k++);
    wc[l] = F(k++); bc[l] = F(k++); swc[l] = F(k++); sbc[l] = F(k++);
    wr[l] = F(k++); br_[l] = F(k++); swr[l] = F(k++); sbr[l] = F(k++);
  }

  // ---- workspace layout ----
  float* ws = (float*)d_ws;
  float* S = ws;                              // 14*1024
  float* D = S + 14 * 1024;                   // 9*1024
  float* bufA = D + 9 * 1024;                 // 2*64*64*512
  float* bufB = bufA + 2 * 64 * 64 * 512;
  float* rgbA = bufB + 2 * 64 * 64 * 512;     // 2*64*64*3
  float* rgbB = rgbA + 2 * 64 * 64 * 3;
  unsigned short* u16 = (unsigned short*)(rgbB + 2 * 64 * 64 * 3);
  unsigned short* xprepA = u16;               // 2*64*64*512
  unsigned short* xprepB = xprepA + 2 * 64 * 64 * 512;
  unsigned short* wT[6];
  {
    unsigned short* p = xprepB + 2 * 64 * 64 * 512;
    int wsz[6] = {9 * 128 * 256, 9 * 256 * 256, 9 * 256 * 512, 9 * 512 * 512, 9 * 512 * 512, 9 * 512 * 512};
    for (int i = 0; i < 6; i++) { wT[i] = p; p += wsz[i]; }
  }

  const int B = 2;
  const int NFa[5] = {64, 128, 256, 512, 512};
  int cprev0[4] = {512, 128, 256, 512};
  int rowu[4] = {1, 6, 6, 6};

  // ---- fused weight prep (6 mfma convs) ----
  {
    WPArgs WA;
    const float* srcs[6] = {wu[1], wc[1], wu[2], wc[2], wu[3], wc[3]};
    int cins[6] = {128, 256, 256, 512, 512, 512};
    int couts[6] = {256, 256, 512, 512, 512, 512};
    int start = 0;
    for (int i = 0; i < 6; i++) {
      WA.d[i] = {srcs[i], wT[i], cins[i], couts[i], start};
      start += couts[i] * cins[i] * 9 / 8;
    }
    WA.total = start;
    wprep_kernel<<<dim3((start + 255) / 256), 256, 0, stream>>>(WA);
  }

  // ---- fused styles (14) ----
  {
    StyleArgs SA;
    SA.d[0] = {sw0, sb0, 0, 512};
    SA.d[1] = {swr0, sbr0, 1, 512};
    for (int l = 0; l < 4; l++) {
      int c = NFa[l + 1];
      SA.d[2 + l * 3] = {swu[l], sbu[l], rowu[l], cprev0[l]};
      SA.d[3 + l * 3] = {swc[l], sbc[l], 5, c};
      SA.d[4 + l * 3] = {swr[l], sbr[l], 6, c};
    }
    style_all_kernel<<<dim3(56), 256, 0, stream>>>(latents, SA, S);
  }

  // ---- fused demods (9) ----
  {
    DemodArgs DA;
    int start = 0;
    auto add = [&](int i, const float* w, int sid, int did, int cin, int cout) {
      DA.d[i] = {w, sid, did, cin, cout, start};
      start += B * (cout >> 6);
    };
    add(0, w0, 0, 0, 512, 512);
    for (int l = 0; l < 4; l++) {
      int c = NFa[l + 1];
      add(1 + l * 2, wu[l], 2 + l * 3, 1 + l * 2, cprev0[l], c);
      add(2 + l * 2, wc[l], 3 + l * 3, 2 + l * 2, c, c);
    }
    demod_all_kernel<<<dim3(start), 256, 0, stream>>>(DA, S, D);
  }

  // ---- conv0 (4x4, fp32) + rgb0 ----
  modconv3x3_kernel<4><<<dim3(4, B), 256, (size_t)3 * 6 * 512 * 4, stream>>>(
      cnst, 0, 4, 4, 512, 9, 512, w0, b0, S, D, noise0, ns0, bufA, 1);
  rgb_kernel<<<dim3(16, B), 64, 0, stream>>>(bufA, 4, 4, 512, wr0, br0, S + 1024, nullptr, rgbA);

  // ---- level 1 (8x8, fp32) ----
  blur_up_kernel<<<dim3(64, B), 256, 0, stream>>>(bufA, 4, 4, 512, bufB);
  modconv3x3_kernel<8><<<dim3(8, B), 256, (size_t)3 * 10 * 512 * 4, stream>>>(
      bufB, (size_t)64 * 512, 8, 8, 512, 9, 128, wu[0], bu[0], S + 2 * 1024, D + 1 * 1024,
      nullptr, nullptr, bufA, 0);
  modconv3x3_kernel<8><<<dim3(8, B), 256, (size_t)3 * 10 * 128 * 4, stream>>>(
      bufA, (size_t)64 * 128, 8, 8, 128, 7, 128, wc[0], bc[0], S + 3 * 1024, D + 2 * 1024,
      nullptr, nullptr, bufB, 0);
  rgb_kernel<<<dim3(64, B), 64, 0, stream>>>(bufB, 8, 8, 128, wr[0], br_[0], S + 4 * 1024, rgbA, rgbB);

  // ---- levels 2..4 (MFMA path) ----
  // level l (loop idx l=1..3): H2 = 16<<(l-1)
  float* ybuf[4] = {bufB, bufA, bufB, bufA};   // c-conv outputs: l=1->bufA, l=2->bufB, l=3->bufA
  float* rgbp = rgbB;
  const float* ysrc = bufB;  // level-1 output
  int Hc = 8;
  for (int l = 1; l < 4; l++) {
    int c = NFa[l + 1];
    int cp = cprev0[l];
    int H2 = Hc * 2;
    int WLOG = (H2 == 16) ? 4 : (H2 == 32) ? 5 : 6;
    int wi = (l - 1) * 2;
    // blur + fold u-style -> bf16
    prep_up_kernel<<<dim3(H2 * H2, B), 256, 0, stream>>>(
        ysrc, Hc, cp, S + (2 + l * 3) * 1024, xprepA);
    // u conv: -> bf16 xprepB (folds c-style)
    {
      int PRu = (128 >> WLOG) + 2, PCu = H2 + 2;
      size_t lds = (size_t)(PRu * PCu * 40 + 64 * 296) * 2;
      mfma_conv_kernel<<<dim3((B * H2 * H2) / 128, c >> 6), 256, lds, stream>>>(
          xprepA, H2, WLOG, cp, c, wT[wi], bu[l], D + (1 + l * 2) * 1024,
          nullptr, xprepB, S + (3 + l * 3) * 1024);
    }
    // c conv: -> fp32 y
    float* yo = ybuf[l];
    {
      int PRu = (128 >> WLOG) + 2, PCu = H2 + 2;
      size_t lds = (size_t)(PRu * PCu * 40 + 64 * 296) * 2;
      mfma_conv_kernel<<<dim3((B * H2 * H2) / 128, c >> 6), 256, lds, stream>>>(
          xprepB, H2, WLOG, c, c, wT[wi + 1], bc[l], D + (2 + l * 2) * 1024,
          yo, nullptr, nullptr);
    }
    // rgb
    float* rout = (l == 3) ? (float*)d_out : ((rgbp == rgbA) ? rgbB : rgbA);
    rgb_kernel<<<dim3(H2 * H2, B), 64, 0, stream>>>(
        yo, H2, H2, c, wr[l], br_[l], S + (4 + l * 3) * 1024, rgbp, rout);
    rgbp = (rout == rgbA) ? rgbA : rgbB;
    ysrc = yo;
    Hc = H2;
  }
  (void)in_sizes; (void)n_in; (void)out_size; (void)ws_size;
}

// Round 4
// 1198.372 us; speedup vs baseline: 23.8514x; 1.8581x over previous
//
#include <hip/hip_runtime.h>

#define LEAKY(v) ((v) > 0.f ? (v) : 0.01f * (v))

typedef __attribute__((ext_vector_type(8))) short bf16x8;
typedef __attribute__((ext_vector_type(4))) float floatx4;

__device__ inline unsigned short f2bf(float f) {
  unsigned u = __float_as_uint(f);
  unsigned r = u + 0x7FFFu + ((u >> 16) & 1u);
  return (unsigned short)(r >> 16);
}

// ---------------- fused style: all 14 affines in one dispatch ----------------
struct StyleDesc { const float* sw; const float* sb; int row; int cin; };
struct StyleArgs { StyleDesc d[14]; };

__global__ __launch_bounds__(256) void style_all_kernel(
    const float* __restrict__ lat, StyleArgs A, float* __restrict__ S)
{
  int bid = blockIdx.x;
  int chunk = bid & 1, b = (bid >> 1) & 1, sid = bid >> 2;
  StyleDesc d = A.d[sid];
  int ci = chunk * 256 + threadIdx.x;
  if (ci >= d.cin) return;
  const float* l = lat + (size_t)b * (10 * 512) + d.row * 512;
  float acc = d.sb[ci];
  for (int k = 0; k < 512; k += 4) {
    acc += l[k] * d.sw[(size_t)k * d.cin + ci];
    acc += l[k + 1] * d.sw[(size_t)(k + 1) * d.cin + ci];
    acc += l[k + 2] * d.sw[(size_t)(k + 2) * d.cin + ci];
    acc += l[k + 3] * d.sw[(size_t)(k + 3) * d.cin + ci];
  }
  S[sid * 1024 + b * 512 + ci] = acc;
}

// ---------------- fused demod: all 9 in one dispatch ----------------
struct DemodDesc { const float* w; int sid; int did; int cin; int cout; int start; };
struct DemodArgs { DemodDesc d[9]; };

__global__ __launch_bounds__(256) void demod_all_kernel(
    DemodArgs A, const float* __restrict__ S, float* __restrict__ Dout)
{
  __shared__ float red[256];
  int bid = blockIdx.x;
  int c = 0;
  while (c < 8 && bid >= A.d[c + 1].start) c++;
  DemodDesc d = A.d[c];
  int rel = bid - d.start;
  int chunksPerB = d.cout >> 6;
  int b = rel / chunksPerB;
  int coc = rel - b * chunksPerB;
  int co = coc * 64 + (threadIdx.x & 63);
  int slice = threadIdx.x >> 6;
  const float* sv = S + d.sid * 1024 + b * 512;
  int R = 9 * d.cin, cmask = d.cin - 1;
  float acc = 0.f;
  for (int r = slice; r < R; r += 4) {
    float wv = d.w[(size_t)r * d.cout + co];
    float s = sv[r & cmask];
    float t = wv * s;
    acc += t * t;
  }
  red[threadIdx.x] = acc;
  __syncthreads();
  if (threadIdx.x < 64) {
    float a = red[threadIdx.x] + red[threadIdx.x + 64] + red[threadIdx.x + 128] + red[threadIdx.x + 192];
    Dout[d.did * 1024 + b * 512 + co] = rsqrtf(a + 1e-8f);
  }
}

// ---------------- fused weight prep: fp32 [kt][ci][co] -> bf16 [co][k'] ----------------
struct WPD { const float* src; unsigned short* dst; int cin; int cout; int start; };
struct WPArgs { WPD d[6]; int total; };

__global__ __launch_bounds__(256) void wprep_kernel(WPArgs A)
{
  int chunk = blockIdx.x * 256 + threadIdx.x;
  if (chunk >= A.total) return;
  int c = 0;
  while (c < 5 && chunk >= A.d[c + 1].start) c++;
  WPD d = A.d[c];
  int rel = chunk - d.start;
  int cpc = d.cin * 9 / 8;
  int co = rel / cpc;
  int k0 = (rel - co * cpc) * 8;
  int cig = k0 / 288;
  int r = k0 - cig * 288;
  int kt = r >> 5;
  int cibase = cig * 32 + (r & 31);
  const float* sp = d.src + (size_t)(kt * d.cin + cibase) * d.cout + co;
  size_t st = d.cout;
  unsigned r0 = f2bf(sp[0]) | ((unsigned)f2bf(sp[st]) << 16);
  unsigned r1 = f2bf(sp[2 * st]) | ((unsigned)f2bf(sp[3 * st]) << 16);
  unsigned r2 = f2bf(sp[4 * st]) | ((unsigned)f2bf(sp[5 * st]) << 16);
  unsigned r3 = f2bf(sp[6 * st]) | ((unsigned)f2bf(sp[7 * st]) << 16);
  uint4 v = {r0, r1, r2, r3};
  *(uint4*)(d.dst + (size_t)co * (d.cin * 9) + k0) = v;
}

// ---------------- blur_up taps ----------------
__device__ inline void blur_taps(int o, int* r0, int* r1, float* w0, float* w1)
{
  if ((o & 1) == 0) { *r0 = (o >> 1) - 1; *w0 = 1.f; *r1 = (o >> 1); *w1 = 3.f; }
  else              { *r0 = (o - 1) >> 1; *w0 = 3.f; *r1 = ((o - 1) >> 1) + 1; *w1 = 1.f; }
}

__global__ __launch_bounds__(256) void blur_up_kernel(
    const float* __restrict__ x, int H, int W, int C, float* __restrict__ out)
{
  int b = blockIdx.y;
  int W2 = W * 2;
  int pix = blockIdx.x;
  int oy = pix / W2, ox = pix % W2;
  int ry0, ry1, rx0, rx1; float wy0, wy1, wx0, wx1;
  blur_taps(oy, &ry0, &ry1, &wy0, &wy1);
  blur_taps(ox, &rx0, &rx1, &wx0, &wx1);
  bool vy0 = (ry0 >= 0 && ry0 < H), vy1 = (ry1 >= 0 && ry1 < H);
  bool vx0 = (rx0 >= 0 && rx0 < W), vx1 = (rx1 >= 0 && rx1 < W);
  const float* base = x + (size_t)b * H * W * C;
  float* ob = out + (((size_t)b * W2 + oy) * W2 + ox) * C;
  for (int c = threadIdx.x; c < C; c += 256) {
    float acc = 0.f;
    if (vy0) {
      const float* r = base + (size_t)(ry0 * W) * C;
      if (vx0) acc += wy0 * wx0 * r[(size_t)rx0 * C + c];
      if (vx1) acc += wy0 * wx1 * r[(size_t)rx1 * C + c];
    }
    if (vy1) {
      const float* r = base + (size_t)(ry1 * W) * C;
      if (vx0) acc += wy1 * wx0 * r[(size_t)rx0 * C + c];
      if (vx1) acc += wy1 * wx1 * r[(size_t)rx1 * C + c];
    }
    ob[c] = acc * (1.f / 16.f);
  }
}

// ---------------- prep_up: blur_up + style fold + bf16 cast ----------------
__global__ __launch_bounds__(256) void prep_up_kernel(
    const float* __restrict__ y, int Hc, int C,
    const float* __restrict__ s, unsigned short* __restrict__ out)
{
  int b = blockIdx.y;
  int W2 = Hc * 2;
  int pix = blockIdx.x;
  int oy = pix / W2, ox = pix - oy * W2;
  int ry0, ry1, rx0, rx1; float wy0, wy1, wx0, wx1;
  blur_taps(oy, &ry0, &ry1, &wy0, &wy1);
  blur_taps(ox, &rx0, &rx1, &wx0, &wx1);
  bool vy0 = (ry0 >= 0 && ry0 < Hc), vy1 = (ry1 >= 0 && ry1 < Hc);
  bool vx0 = (rx0 >= 0 && rx0 < Hc), vx1 = (rx1 >= 0 && rx1 < Hc);
  const float* base = y + (size_t)b * Hc * Hc * C;
  unsigned short* ob = out + (((size_t)b * W2 + oy) * W2 + ox) * C;
  const float* sv = s + b * 512;
  for (int c = threadIdx.x; c < C; c += 256) {
    float acc = 0.f;
    if (vy0) {
      const float* r = base + (size_t)(ry0 * Hc) * C;
      if (vx0) acc += wy0 * wx0 * r[(size_t)rx0 * C + c];
      if (vx1) acc += wy0 * wx1 * r[(size_t)rx1 * C + c];
    }
    if (vy1) {
      const float* r = base + (size_t)(ry1 * Hc) * C;
      if (vx0) acc += wy1 * wx0 * r[(size_t)rx0 * C + c];
      if (vx1) acc += wy1 * wx1 * r[(size_t)rx1 * C + c];
    }
    ob[c] = f2bf(acc * (1.f / 16.f) * sv[c]);
  }
}

// ---------------- MFMA implicit-GEMM 3x3 conv (levels 2..4) ----------------
__global__ __launch_bounds__(256) void mfma_conv_kernel(
    const unsigned short* __restrict__ xp, int H, int WLOG, int Cin, int Cout,
    const unsigned short* __restrict__ wT,
    const float* __restrict__ bias, const float* __restrict__ dmod,
    float* __restrict__ outF, unsigned short* __restrict__ outBf,
    const float* __restrict__ sNext)
{
  extern __shared__ unsigned short sm[];
  const int W = 1 << WLOG;
  const int Rt = 128 >> WLOG;
  const int PR = Rt + 2, PC = W + 2;
  const int patchU = PR * PC * 40;
  unsigned short* Bw = sm + patchU;

  const int tid = threadIdx.x;
  const int wave = tid >> 6;
  const int lane = tid & 63;
  const int q = lane >> 4;
  const int l15 = lane & 15;

  const int HW = H << WLOG;
  const int m0 = blockIdx.x << 7;
  const int b = m0 / HW;
  const int y0 = (m0 - b * HW) >> WLOG;
  const int co0 = blockIdx.y << 6;
  const int Kp = Cin * 9;
  const unsigned short* xb = xp + (size_t)b * HW * Cin;

  const int pSlots = PR * PC * 4;
  int pLds[5], pSrc[5];
#pragma unroll
  for (int i = 0; i < 5; i++) {
    int sidx = tid + i * 256;
    pLds[i] = -1; pSrc[i] = -1;
    if (sidx < pSlots) {
      int pidx = sidx >> 2, part = sidx & 3;
      int pr = pidx / PC, pc = pidx - pr * PC;
      int gy = y0 + pr - 1, gx = pc - 1;
      pLds[i] = pidx * 40 + part * 8;
      if ((unsigned)gy < (unsigned)H && (unsigned)gx < (unsigned)W)
        pSrc[i] = ((gy << WLOG) + gx) * Cin + part * 8;
    }
  }
  int bLds[9], bSrc[9];
#pragma unroll
  for (int i = 0; i < 9; i++) {
    int sidx = tid + i * 256;
    int n = sidx / 36, c16 = sidx - n * 36;
    bLds[i] = n * 296 + c16 * 8;
    bSrc[i] = (co0 + n) * Kp + c16 * 8;
  }

  floatx4 zero = {0.f, 0.f, 0.f, 0.f};
  floatx4 acc[2][4];
#pragma unroll
  for (int mi = 0; mi < 2; mi++)
#pragma unroll
    for (int s = 0; s < 4; s++) acc[mi][s] = zero;

  const int mA0 = wave * 32 + l15;
  const int mA1 = mA0 + 16;
  const int aBase0 = ((mA0 >> WLOG) * PC + (mA0 & (W - 1))) * 40 + q * 8;
  const int aBase1 = ((mA1 >> WLOG) * PC + (mA1 & (W - 1))) * 40 + q * 8;
  const int bBase = l15 * 296 + q * 8;

  const int nGroups = Cin >> 5;
  for (int g = 0; g < nGroups; g++) {
    __syncthreads();
    {
      const int gci = g << 5;
#pragma unroll
      for (int i = 0; i < 5; i++) {
        if (pLds[i] >= 0) {
          uint4 v = {0u, 0u, 0u, 0u};
          if (pSrc[i] >= 0) v = *(const uint4*)(xb + pSrc[i] + gci);
          *(uint4*)(sm + pLds[i]) = v;
        }
      }
      const int gw = g * 288;
#pragma unroll
      for (int i = 0; i < 9; i++)
        *(uint4*)(Bw + bLds[i]) = *(const uint4*)(wT + bSrc[i] + gw);
    }
    __syncthreads();
#pragma unroll
    for (int kt = 0; kt < 9; kt++) {
      const int ky = kt / 3, kx = kt - (kt / 3) * 3;
      const int ao = (ky * PC + kx) * 40;
      bf16x8 a0 = *(const bf16x8*)(sm + aBase0 + ao);
      bf16x8 a1 = *(const bf16x8*)(sm + aBase1 + ao);
      const int bo = bBase + kt * 32;
#pragma unroll
      for (int s = 0; s < 4; s++) {
        bf16x8 bb = *(const bf16x8*)(Bw + bo + s * (16 * 296));
        acc[0][s] = __builtin_amdgcn_mfma_f32_16x16x32_bf16(a0, bb, acc[0][s], 0, 0, 0);
        acc[1][s] = __builtin_amdgcn_mfma_f32_16x16x32_bf16(a1, bb, acc[1][s], 0, 0, 0);
      }
    }
  }

#pragma unroll
  for (int s = 0; s < 4; s++) {
    const int co = co0 + s * 16 + l15;
    const float dm = dmod[b * 512 + co];
    const float bv = bias[co];
    const float sn = sNext ? sNext[b * 512 + co] : 0.f;
#pragma unroll
    for (int mi = 0; mi < 2; mi++) {
#pragma unroll
      for (int r = 0; r < 4; r++) {
        const int mloc = wave * 32 + mi * 16 + q * 4 + r;
        const int py = y0 + (mloc >> WLOG);
        const int px = mloc & (W - 1);
        const size_t oidx = (((size_t)b * H + py) * W + px) * Cout + co;
        const float v = acc[mi][s][r] * dm + bv;
        if (outF) outF[oidx] = v;
        if (outBf) outBf[oidx] = f2bf(v * sn);
      }
    }
  }
}

// ---------------- split-K fp32 3x3 modulated conv (4x4 / 8x8 layers) ----------------
// grid: (rowBlocks, B, nz). Each z covers ci range [z<<ciChunkLog, (z+1)<<ciChunkLog).
// Writes partials [z][b][pix][co] (no demod/bias) -- epilogue reduces.
template<int PIX>
__global__ __launch_bounds__(256) void modconv_splitk_kernel(
    const float* __restrict__ x, size_t xBStride, int H, int W, int Cin, int cinShift,
    int Cout, int ciChunkLog,
    const float* __restrict__ w, const float* __restrict__ s,
    float* __restrict__ partial)
{
  extern __shared__ float lds[];
  const int COLS = PIX + 2;
  const int tid = threadIdx.x;
  const int nthr = blockDim.x;
  const int b = blockIdx.y;
  const int z = blockIdx.z;
  const int nci = 1 << ciChunkLog;
  const int ci0 = z << ciChunkLog;
  const int wb = W / PIX;
  const int row = blockIdx.x / wb;
  const int x0 = (blockIdx.x % wb) * PIX;

  const float* xb = x + (size_t)b * xBStride;
  const float* sv = s + b * 512;

  const int tot = 3 * COLS << ciChunkLog;
  for (int idx = tid; idx < tot; idx += nthr) {
    int cil = idx & (nci - 1);
    int t = idx >> ciChunkLog;
    int col = t % COLS;
    int ry = t / COLS;
    int gy = row + ry - 1;
    int gx = x0 + col - 1;
    float v = 0.f;
    if (gy >= 0 && gy < H && gx >= 0 && gx < W)
      v = xb[((size_t)(gy * W + gx) << cinShift) + ci0 + cil] * sv[ci0 + cil];
    lds[idx] = v;
  }
  __syncthreads();

  float acc0[PIX];
  float acc1[PIX];
#pragma unroll
  for (int p = 0; p < PIX; p++) { acc0[p] = 0.f; acc1[p] = 0.f; }
  const int co0 = tid;
  const int co1 = tid + nthr;
  const bool a0 = co0 < Cout;
  const bool a1 = co1 < Cout;

  const float4* ldsv = (const float4*)lds;
  const int cin4Shift = ciChunkLog - 2;

  for (int kt = 0; kt < 9; kt++) {
    int ky = kt / 3, kx = kt % 3;
    const float* wr = w + ((size_t)(kt << cinShift) + ci0) * Cout + co0;
    for (int c4 = 0; c4 < (nci >> 2); c4++) {
      float wA0 = 0.f, wA1 = 0.f, wA2 = 0.f, wA3 = 0.f;
      float wB0 = 0.f, wB1 = 0.f, wB2 = 0.f, wB3 = 0.f;
      int d01 = co1 - co0;
      if (a0) { wA0 = wr[0]; }
      if (a1) { wB0 = wr[d01]; }
      wr += Cout;
      if (a0) { wA1 = wr[0]; }
      if (a1) { wB1 = wr[d01]; }
      wr += Cout;
      if (a0) { wA2 = wr[0]; }
      if (a1) { wB2 = wr[d01]; }
      wr += Cout;
      if (a0) { wA3 = wr[0]; }
      if (a1) { wB3 = wr[d01]; }
      wr += Cout;
#pragma unroll
      for (int p = 0; p < PIX; p++) {
        float4 v = ldsv[((ky * COLS + kx + p) << cin4Shift) + c4];
        acc0[p] += v.x * wA0; acc0[p] += v.y * wA1; acc0[p] += v.z * wA2; acc0[p] += v.w * wA3;
        acc1[p] += v.x * wB0; acc1[p] += v.y * wB1; acc1[p] += v.z * wB2; acc1[p] += v.w * wB3;
      }
    }
  }

  const int HW = H * W;
  float* pb = partial + ((size_t)(z * gridDim.y + b) * HW + row * W + x0) * Cout;
#pragma unroll
  for (int p = 0; p < PIX; p++) {
    if (a0) pb[(size_t)p * Cout + co0] = acc0[p];
    if (a1) pb[(size_t)p * Cout + co1] = acc1[p];
  }
}

// ---------------- splitk epilogue: sum z partials, demod*acc+bias (+noise)(+leaky) ----------------
__global__ __launch_bounds__(256) void splitk_epi_kernel(
    const float* __restrict__ partial, int nz, int M, int Cout, int HW,
    const float* __restrict__ dmod, const float* __restrict__ bias,
    const float* __restrict__ noise, const float* __restrict__ ns,
    float* __restrict__ out, int doAct)
{
  int idx = blockIdx.x * 256 + threadIdx.x;
  if (idx >= M * Cout) return;
  int m = idx / Cout;
  int co = idx - m * Cout;
  int b = m / HW;
  float acc = 0.f;
  for (int z = 0; z < nz; z++) acc += partial[(size_t)z * M * Cout + idx];
  float v = acc * dmod[b * 512 + co] + bias[co];
  if (noise) v += ns[0] * noise[m];
  if (doAct) v = LEAKY(v);
  out[idx] = v;
}

// ---------------- to_rgb: 1x1 modconv (no demod) + leaky + blur-up skip add ----------------
__global__ __launch_bounds__(64) void rgb_kernel(
    const float* __restrict__ y, int H, int W, int Cin,
    const float* __restrict__ w, const float* __restrict__ bias,
    const float* __restrict__ s, const float* __restrict__ prev,
    float* __restrict__ out)
{
  int b = blockIdx.y;
  int pix = blockIdx.x;
  int oy = pix / W, ox = pix % W;
  const float* xp = y + (((size_t)b * H + oy) * W + ox) * Cin;
  const float* sv = s + b * 512;
  float p0 = 0.f, p1 = 0.f, p2 = 0.f;
  for (int ci = threadIdx.x; ci < Cin; ci += 64) {
    float v = xp[ci] * sv[ci];
    p0 += v * w[ci * 3 + 0];
    p1 += v * w[ci * 3 + 1];
    p2 += v * w[ci * 3 + 2];
  }
  for (int off = 32; off > 0; off >>= 1) {
    p0 += __shfl_down(p0, off);
    p1 += __shfl_down(p1, off);
    p2 += __shfl_down(p2, off);
  }
  if (threadIdx.x == 0) {
    float r0 = p0 + bias[0], r1 = p1 + bias[1], r2 = p2 + bias[2];
    float sk0 = 0.f, sk1 = 0.f, sk2 = 0.f;
    if (prev) {
      int Hp = H >> 1, Wp = W >> 1;
      int ry0, ry1, rx0, rx1; float wy0, wy1, wx0, wx1;
      blur_taps(oy, &ry0, &ry1, &wy0, &wy1);
      blur_taps(ox, &rx0, &rx1, &wx0, &wx1);
      bool vy0 = (ry0 >= 0 && ry0 < Hp), vy1 = (ry1 >= 0 && ry1 < Hp);
      bool vx0 = (rx0 >= 0 && rx0 < Wp), vx1 = (rx1 >= 0 && rx1 < Wp);
      const float* base = prev + (size_t)b * Hp * Wp * 3;
      float a0 = 0.f, a1 = 0.f, a2 = 0.f;
      if (vy0 && vx0) { const float* qq = base + (size_t)(ry0 * Wp + rx0) * 3; float wg = wy0 * wx0; a0 += wg * qq[0]; a1 += wg * qq[1]; a2 += wg * qq[2]; }
      if (vy0 && vx1) { const float* qq = base + (size_t)(ry0 * Wp + rx1) * 3; float wg = wy0 * wx1; a0 += wg * qq[0]; a1 += wg * qq[1]; a2 += wg * qq[2]; }
      if (vy1 && vx0) { const float* qq = base + (size_t)(ry1 * Wp + rx0) * 3; float wg = wy1 * wx0; a0 += wg * qq[0]; a1 += wg * qq[1]; a2 += wg * qq[2]; }
      if (vy1 && vx1) { const float* qq = base + (size_t)(ry1 * Wp + rx1) * 3; float wg = wy1 * wx1; a0 += wg * qq[0]; a1 += wg * qq[1]; a2 += wg * qq[2]; }
      sk0 = a0 * (1.f / 16.f); sk1 = a1 * (1.f / 16.f); sk2 = a2 * (1.f / 16.f);
    }
    float* ob = out + (((size_t)b * H + oy) * W + ox) * 3;
    ob[0] = LEAKY(r0) + sk0;
    ob[1] = LEAKY(r1) + sk1;
    ob[2] = LEAKY(r2) + sk2;
  }
}

extern "C" void kernel_launch(void* const* d_in, const int* in_sizes, int n_in,
                              void* d_out, int out_size, void* d_ws, size_t ws_size,
                              hipStream_t stream)
{
  auto F = [&](int k) { return (const float*)d_in[k]; };
  const float* latents = F(0);
  const float* cnst = F(1);
  const float* w0 = F(2);  const float* b0 = F(3);  const float* sw0 = F(4);  const float* sb0 = F(5);
  const float* ns0 = F(6); const float* noise0 = F(7);
  const float* wr0 = F(8); const float* br0 = F(9); const float* swr0 = F(10); const float* sbr0 = F(11);
  const float *wu[4], *bu[4], *swu[4], *sbu[4];
  const float *wc[4], *bc[4], *swc[4], *sbc[4];
  const float *wr[4], *br_[4], *swr[4], *sbr[4];
  int k = 12;
  for (int l = 0; l < 4; l++) {
    wu[l] = F(k++); bu[l] = F(k++); swu[l] = F(k++); sbu[l] = F(k++);
    wc[l] = F(k++); bc[l] = F(k++); swc[l] = F(k++); sbc[l] = F(k++);
    wr[l] = F(k++); br_[l] = F(k++); swr[l] = F(k++); sbr[l] = F(k++);
  }

  // ---- workspace layout ----
  float* ws = (float*)d_ws;
  float* S = ws;                              // 14*1024
  float* D = S + 14 * 1024;                   // 9*1024
  float* bufA = D + 9 * 1024;                 // 2*64*64*512
  float* bufB = bufA + 2 * 64 * 64 * 512;
  float* rgbA = bufB + 2 * 64 * 64 * 512;     // 2*64*64*3
  float* rgbB = rgbA + 2 * 64 * 64 * 3;
  float* P = rgbB + 2 * 64 * 64 * 3;          // split-K partials: 131072 floats
  unsigned short* u16 = (unsigned short*)(P + 131072);
  unsigned short* xprepA = u16;               // 2*64*64*512
  unsigned short* xprepB = xprepA + 2 * 64 * 64 * 512;
  unsigned short* wT[6];
  {
    unsigned short* p = xprepB + 2 * 64 * 64 * 512;
    int wsz[6] = {9 * 128 * 256, 9 * 256 * 256, 9 * 256 * 512, 9 * 512 * 512, 9 * 512 * 512, 9 * 512 * 512};
    for (int i = 0; i < 6; i++) { wT[i] = p; p += wsz[i]; }
  }

  const int B = 2;
  const int NFa[5] = {64, 128, 256, 512, 512};
  int cprev0[4] = {512, 128, 256, 512};
  int rowu[4] = {1, 6, 6, 6};

  // ---- fused weight prep (6 mfma convs) ----
  {
    WPArgs WA;
    const float* srcs[6] = {wu[1], wc[1], wu[2], wc[2], wu[3], wc[3]};
    int cins[6] = {128, 256, 256, 512, 512, 512};
    int couts[6] = {256, 256, 512, 512, 512, 512};
    int start = 0;
    for (int i = 0; i < 6; i++) {
      WA.d[i] = {srcs[i], wT[i], cins[i], couts[i], start};
      start += couts[i] * cins[i] * 9 / 8;
    }
    WA.total = start;
    wprep_kernel<<<dim3((start + 255) / 256), 256, 0, stream>>>(WA);
  }

  // ---- fused styles (14) ----
  {
    StyleArgs SA;
    SA.d[0] = {sw0, sb0, 0, 512};
    SA.d[1] = {swr0, sbr0, 1, 512};
    for (int l = 0; l < 4; l++) {
      int c = NFa[l + 1];
      SA.d[2 + l * 3] = {swu[l], sbu[l], rowu[l], cprev0[l]};
      SA.d[3 + l * 3] = {swc[l], sbc[l], 5, c};
      SA.d[4 + l * 3] = {swr[l], sbr[l], 6, c};
    }
    style_all_kernel<<<dim3(56), 256, 0, stream>>>(latents, SA, S);
  }

  // ---- fused demods (9) ----
  {
    DemodArgs DA;
    int start = 0;
    auto add = [&](int i, const float* w, int sid, int did, int cin, int cout) {
      DA.d[i] = {w, sid, did, cin, cout, start};
      start += B * (cout >> 6);
    };
    add(0, w0, 0, 0, 512, 512);
    for (int l = 0; l < 4; l++) {
      int c = NFa[l + 1];
      add(1 + l * 2, wu[l], 2 + l * 3, 1 + l * 2, cprev0[l], c);
      add(2 + l * 2, wc[l], 3 + l * 3, 2 + l * 2, c, c);
    }
    demod_all_kernel<<<dim3(start), 256, 0, stream>>>(DA, S, D);
  }

  // ---- conv0 (4x4, fp32 split-K z=8, ci-chunk 64) + epi + rgb0 ----
  modconv_splitk_kernel<4><<<dim3(4, B, 8), 256, (size_t)3 * 6 * 64 * 4, stream>>>(
      cnst, 0, 4, 4, 512, 9, 512, 6, w0, S, P);
  splitk_epi_kernel<<<dim3((32 * 512 + 255) / 256), 256, 0, stream>>>(
      P, 8, 32, 512, 16, D, b0, noise0, ns0, bufA, 1);
  rgb_kernel<<<dim3(16, B), 64, 0, stream>>>(bufA, 4, 4, 512, wr0, br0, S + 1024, nullptr, rgbA);

  // ---- level 1 (8x8, fp32 split-K) ----
  blur_up_kernel<<<dim3(64, B), 256, 0, stream>>>(bufA, 4, 4, 512, bufB);
  // u1: Cin=512 (z=8, chunk 64), Cout=128 -> 128-thread blocks
  modconv_splitk_kernel<8><<<dim3(8, B, 8), 128, (size_t)3 * 10 * 64 * 4, stream>>>(
      bufB, (size_t)64 * 512, 8, 8, 512, 9, 128, 6, wu[0], S + 2 * 1024, P);
  splitk_epi_kernel<<<dim3((128 * 128 + 255) / 256), 256, 0, stream>>>(
      P, 8, 128, 128, 64, D + 1 * 1024, bu[0], nullptr, nullptr, bufA, 0);
  // c1: Cin=128 (z=4, chunk 32), Cout=128
  modconv_splitk_kernel<8><<<dim3(8, B, 4), 128, (size_t)3 * 10 * 32 * 4, stream>>>(
      bufA, (size_t)64 * 128, 8, 8, 128, 7, 128, 5, wc[0], S + 3 * 1024, P);
  splitk_epi_kernel<<<dim3((128 * 128 + 255) / 256), 256, 0, stream>>>(
      P, 4, 128, 128, 64, D + 2 * 1024, bc[0], nullptr, nullptr, bufB, 0);
  rgb_kernel<<<dim3(64, B), 64, 0, stream>>>(bufB, 8, 8, 128, wr[0], br_[0], S + 4 * 1024, rgbA, rgbB);

  // ---- levels 2..4 (MFMA path) ----
  float* ybuf[4] = {bufB, bufA, bufB, bufA};
  float* rgbp = rgbB;
  const float* ysrc = bufB;
  int Hc = 8;
  for (int l = 1; l < 4; l++) {
    int c = NFa[l + 1];
    int cp = cprev0[l];
    int H2 = Hc * 2;
    int WLOG = (H2 == 16) ? 4 : (H2 == 32) ? 5 : 6;
    int wi = (l - 1) * 2;
    prep_up_kernel<<<dim3(H2 * H2, B), 256, 0, stream>>>(
        ysrc, Hc, cp, S + (2 + l * 3) * 1024, xprepA);
    {
      int PRu = (128 >> WLOG) + 2, PCu = H2 + 2;
      size_t lds = (size_t)(PRu * PCu * 40 + 64 * 296) * 2;
      mfma_conv_kernel<<<dim3((B * H2 * H2) / 128, c >> 6), 256, lds, stream>>>(
          xprepA, H2, WLOG, cp, c, wT[wi], bu[l], D + (1 + l * 2) * 1024,
          nullptr, xprepB, S + (3 + l * 3) * 1024);
    }
    float* yo = ybuf[l];
    {
      int PRu = (128 >> WLOG) + 2, PCu = H2 + 2;
      size_t lds = (size_t)(PRu * PCu * 40 + 64 * 296) * 2;
      mfma_conv_kernel<<<dim3((B * H2 * H2) / 128, c >> 6), 256, lds, stream>>>(
          xprepB, H2, WLOG, c, c, wT[wi + 1], bc[l], D + (2 + l * 2) * 1024,
          yo, nullptr, nullptr);
    }
    float* rout = (l == 3) ? (float*)d_out : ((rgbp == rgbA) ? rgbB : rgbA);
    rgb_kernel<<<dim3(H2 * H2, B), 64, 0, stream>>>(
        yo, H2, H2, c, wr[l], br_[l], S + (4 + l * 3) * 1024, rgbp, rout);
    rgbp = (rout == rgbA) ? rgbA : rgbB;
    ysrc = yo;
    Hc = H2;
  }
  (void)in_sizes; (void)n_in; (void)out_size; (void)ws_size;
}

// Round 5
// 753.055 us; speedup vs baseline: 37.9559x; 1.5913x over previous
//
#include <hip/hip_runtime.h>

#define LEAKY(v) ((v) > 0.f ? (v) : 0.01f * (v))

typedef __attribute__((ext_vector_type(8))) short bf16x8;
typedef __attribute__((ext_vector_type(4))) float floatx4;

__device__ inline unsigned short f2bf(float f) {
  unsigned u = __float_as_uint(f);
  unsigned r = u + 0x7FFFu + ((u >> 16) & 1u);
  return (unsigned short)(r >> 16);
}

// ---------------- fused style: all 14 affines in one dispatch ----------------
struct StyleDesc { const float* sw; const float* sb; int row; int cin; };
struct StyleArgs { StyleDesc d[14]; };

__global__ __launch_bounds__(256) void style_all_kernel(
    const float* __restrict__ lat, StyleArgs A, float* __restrict__ S)
{
  int bid = blockIdx.x;
  int chunk = bid & 1, b = (bid >> 1) & 1, sid = bid >> 2;
  StyleDesc d = A.d[sid];
  int ci = chunk * 256 + threadIdx.x;
  if (ci >= d.cin) return;
  const float* l = lat + (size_t)b * (10 * 512) + d.row * 512;
  // 8 independent accumulators -> 8 loads in flight
  float a0 = 0.f, a1 = 0.f, a2 = 0.f, a3 = 0.f, a4 = 0.f, a5 = 0.f, a6 = 0.f, a7 = 0.f;
  const float* wp = d.sw + ci;
  size_t st = d.cin;
  for (int k = 0; k < 512; k += 8) {
    a0 += l[k] * wp[0];
    a1 += l[k + 1] * wp[st];
    a2 += l[k + 2] * wp[2 * st];
    a3 += l[k + 3] * wp[3 * st];
    a4 += l[k + 4] * wp[4 * st];
    a5 += l[k + 5] * wp[5 * st];
    a6 += l[k + 6] * wp[6 * st];
    a7 += l[k + 7] * wp[7 * st];
    wp += 8 * st;
  }
  S[sid * 1024 + b * 512 + ci] = d.sb[ci] + ((a0 + a1) + (a2 + a3)) + ((a4 + a5) + (a6 + a7));
}

// ---------------- W2[ci][co] = sum_kt w[kt][ci][co]^2  (batch-independent) ----------------
struct W2D { const float* w; int cinLog; int coutLog; int start; int w2off; };
struct W2Args { W2D d[9]; int total4; };

__global__ __launch_bounds__(256) void w2_kernel(W2Args A, float* __restrict__ W2)
{
  int idx = blockIdx.x * 256 + threadIdx.x;
  if (idx >= A.total4) return;
  int c = 0;
  while (c < 8 && idx >= A.d[c + 1].start) c++;
  W2D d = A.d[c];
  int rel = idx - d.start;
  int co4Log = d.coutLog - 2;
  int ci = rel >> co4Log;
  int co = (rel & ((1 << co4Log) - 1)) << 2;
  int cout = 1 << d.coutLog;
  size_t ktStride = (size_t)(1 << d.cinLog) << d.coutLog;
  const float* p = d.w + ((size_t)ci << d.coutLog) + co;
  float4 acc = {0.f, 0.f, 0.f, 0.f};
#pragma unroll
  for (int kt = 0; kt < 9; kt++) {
    float4 v = *(const float4*)(p + kt * ktStride);
    acc.x += v.x * v.x; acc.y += v.y * v.y; acc.z += v.z * v.z; acc.w += v.w * v.w;
  }
  *(float4*)(W2 + d.w2off + ((size_t)ci << d.coutLog) + co) = acc;
  (void)cout;
}

// ---------------- demod2: d[b,co] = rsqrt(sum_ci s^2 * W2 + 1e-8) ----------------
struct D2D { int w2off; int sid; int did; int cin; int cout; int start; };
struct D2Args { D2D d[9]; };

__global__ __launch_bounds__(256) void demod2_all_kernel(
    D2Args A, const float* __restrict__ W2, const float* __restrict__ S,
    float* __restrict__ Dout)
{
  __shared__ float red[256];
  int bid = blockIdx.x;
  int c = 0;
  while (c < 8 && bid >= A.d[c + 1].start) c++;
  D2D d = A.d[c];
  int rel = bid - d.start;
  int chunksPerB = d.cout >> 6;
  int b = rel / chunksPerB;
  int coc = rel - b * chunksPerB;
  int co = coc * 64 + (threadIdx.x & 63);
  int slice = threadIdx.x >> 6;
  const float* sv = S + d.sid * 1024 + b * 512;
  const float* wp = W2 + d.w2off + co;
  // slices stride 4; unroll 8 -> 8 outstanding loads
  float a0 = 0.f, a1 = 0.f, a2 = 0.f, a3 = 0.f, a4 = 0.f, a5 = 0.f, a6 = 0.f, a7 = 0.f;
  for (int r = slice; r < d.cin; r += 32) {
    float s0 = sv[r];          a0 += s0 * s0 * wp[(size_t)r * d.cout];
    float s1 = sv[r + 4];      a1 += s1 * s1 * wp[(size_t)(r + 4) * d.cout];
    float s2 = sv[r + 8];      a2 += s2 * s2 * wp[(size_t)(r + 8) * d.cout];
    float s3 = sv[r + 12];     a3 += s3 * s3 * wp[(size_t)(r + 12) * d.cout];
    float s4 = sv[r + 16];     a4 += s4 * s4 * wp[(size_t)(r + 16) * d.cout];
    float s5 = sv[r + 20];     a5 += s5 * s5 * wp[(size_t)(r + 20) * d.cout];
    float s6 = sv[r + 24];     a6 += s6 * s6 * wp[(size_t)(r + 24) * d.cout];
    float s7 = sv[r + 28];     a7 += s7 * s7 * wp[(size_t)(r + 28) * d.cout];
  }
  red[threadIdx.x] = ((a0 + a1) + (a2 + a3)) + ((a4 + a5) + (a6 + a7));
  __syncthreads();
  if (threadIdx.x < 64) {
    float a = red[threadIdx.x] + red[threadIdx.x + 64] + red[threadIdx.x + 128] + red[threadIdx.x + 192];
    Dout[d.did * 1024 + b * 512 + co] = rsqrtf(a + 1e-8f);
  }
}

// ---------------- fused weight prep: fp32 [kt][ci][co] -> bf16 [co][k'] ----------------
struct WPD { const float* src; unsigned short* dst; int cin; int cout; int start; };
struct WPArgs { WPD d[6]; int total; };

__global__ __launch_bounds__(256) void wprep_kernel(WPArgs A)
{
  int chunk = blockIdx.x * 256 + threadIdx.x;
  if (chunk >= A.total) return;
  int c = 0;
  while (c < 5 && chunk >= A.d[c + 1].start) c++;
  WPD d = A.d[c];
  int rel = chunk - d.start;
  int cpc = d.cin * 9 / 8;
  int co = rel / cpc;
  int k0 = (rel - co * cpc) * 8;
  int cig = k0 / 288;
  int r = k0 - cig * 288;
  int kt = r >> 5;
  int cibase = cig * 32 + (r & 31);
  const float* sp = d.src + (size_t)(kt * d.cin + cibase) * d.cout + co;
  size_t st = d.cout;
  unsigned r0 = f2bf(sp[0]) | ((unsigned)f2bf(sp[st]) << 16);
  unsigned r1 = f2bf(sp[2 * st]) | ((unsigned)f2bf(sp[3 * st]) << 16);
  unsigned r2 = f2bf(sp[4 * st]) | ((unsigned)f2bf(sp[5 * st]) << 16);
  unsigned r3 = f2bf(sp[6 * st]) | ((unsigned)f2bf(sp[7 * st]) << 16);
  uint4 v = {r0, r1, r2, r3};
  *(uint4*)(d.dst + (size_t)co * (d.cin * 9) + k0) = v;
}

// ---------------- blur_up taps ----------------
__device__ inline void blur_taps(int o, int* r0, int* r1, float* w0, float* w1)
{
  if ((o & 1) == 0) { *r0 = (o >> 1) - 1; *w0 = 1.f; *r1 = (o >> 1); *w1 = 3.f; }
  else              { *r0 = (o - 1) >> 1; *w0 = 3.f; *r1 = ((o - 1) >> 1) + 1; *w1 = 1.f; }
}

__global__ __launch_bounds__(256) void blur_up_kernel(
    const float* __restrict__ x, int H, int W, int C, float* __restrict__ out)
{
  int b = blockIdx.y;
  int W2 = W * 2;
  int pix = blockIdx.x;
  int oy = pix / W2, ox = pix % W2;
  int ry0, ry1, rx0, rx1; float wy0, wy1, wx0, wx1;
  blur_taps(oy, &ry0, &ry1, &wy0, &wy1);
  blur_taps(ox, &rx0, &rx1, &wx0, &wx1);
  bool vy0 = (ry0 >= 0 && ry0 < H), vy1 = (ry1 >= 0 && ry1 < H);
  bool vx0 = (rx0 >= 0 && rx0 < W), vx1 = (rx1 >= 0 && rx1 < W);
  const float* base = x + (size_t)b * H * W * C;
  float* ob = out + (((size_t)b * W2 + oy) * W2 + ox) * C;
  for (int c = threadIdx.x; c < C; c += 256) {
    float acc = 0.f;
    if (vy0) {
      const float* r = base + (size_t)(ry0 * W) * C;
      if (vx0) acc += wy0 * wx0 * r[(size_t)rx0 * C + c];
      if (vx1) acc += wy0 * wx1 * r[(size_t)rx1 * C + c];
    }
    if (vy1) {
      const float* r = base + (size_t)(ry1 * W) * C;
      if (vx0) acc += wy1 * wx0 * r[(size_t)rx0 * C + c];
      if (vx1) acc += wy1 * wx1 * r[(size_t)rx1 * C + c];
    }
    ob[c] = acc * (1.f / 16.f);
  }
}

// ---------------- prep_up: blur_up + style fold + bf16 cast ----------------
__global__ __launch_bounds__(256) void prep_up_kernel(
    const float* __restrict__ y, int Hc, int C,
    const float* __restrict__ s, unsigned short* __restrict__ out)
{
  int b = blockIdx.y;
  int W2 = Hc * 2;
  int pix = blockIdx.x;
  int oy = pix / W2, ox = pix - oy * W2;
  int ry0, ry1, rx0, rx1; float wy0, wy1, wx0, wx1;
  blur_taps(oy, &ry0, &ry1, &wy0, &wy1);
  blur_taps(ox, &rx0, &rx1, &wx0, &wx1);
  bool vy0 = (ry0 >= 0 && ry0 < Hc), vy1 = (ry1 >= 0 && ry1 < Hc);
  bool vx0 = (rx0 >= 0 && rx0 < Hc), vx1 = (rx1 >= 0 && rx1 < Hc);
  const float* base = y + (size_t)b * Hc * Hc * C;
  unsigned short* ob = out + (((size_t)b * W2 + oy) * W2 + ox) * C;
  const float* sv = s + b * 512;
  for (int c = threadIdx.x; c < C; c += 256) {
    float acc = 0.f;
    if (vy0) {
      const float* r = base + (size_t)(ry0 * Hc) * C;
      if (vx0) acc += wy0 * wx0 * r[(size_t)rx0 * C + c];
      if (vx1) acc += wy0 * wx1 * r[(size_t)rx1 * C + c];
    }
    if (vy1) {
      const float* r = base + (size_t)(ry1 * Hc) * C;
      if (vx0) acc += wy1 * wx0 * r[(size_t)rx0 * C + c];
      if (vx1) acc += wy1 * wx1 * r[(size_t)rx1 * C + c];
    }
    ob[c] = f2bf(acc * (1.f / 16.f) * sv[c]);
  }
}

// ---------------- MFMA implicit-GEMM 3x3 conv (levels 2..4) ----------------
__global__ __launch_bounds__(256) void mfma_conv_kernel(
    const unsigned short* __restrict__ xp, int H, int WLOG, int Cin, int Cout,
    const unsigned short* __restrict__ wT,
    const float* __restrict__ bias, const float* __restrict__ dmod,
    float* __restrict__ outF, unsigned short* __restrict__ outBf,
    const float* __restrict__ sNext)
{
  extern __shared__ unsigned short sm[];
  const int W = 1 << WLOG;
  const int Rt = 128 >> WLOG;
  const int PR = Rt + 2, PC = W + 2;
  const int patchU = PR * PC * 40;
  unsigned short* Bw = sm + patchU;

  const int tid = threadIdx.x;
  const int wave = tid >> 6;
  const int lane = tid & 63;
  const int q = lane >> 4;
  const int l15 = lane & 15;

  const int HW = H << WLOG;
  const int m0 = blockIdx.x << 7;
  const int b = m0 / HW;
  const int y0 = (m0 - b * HW) >> WLOG;
  const int co0 = blockIdx.y << 6;
  const int Kp = Cin * 9;
  const unsigned short* xb = xp + (size_t)b * HW * Cin;

  const int pSlots = PR * PC * 4;
  int pLds[5], pSrc[5];
#pragma unroll
  for (int i = 0; i < 5; i++) {
    int sidx = tid + i * 256;
    pLds[i] = -1; pSrc[i] = -1;
    if (sidx < pSlots) {
      int pidx = sidx >> 2, part = sidx & 3;
      int pr = pidx / PC, pc = pidx - pr * PC;
      int gy = y0 + pr - 1, gx = pc - 1;
      pLds[i] = pidx * 40 + part * 8;
      if ((unsigned)gy < (unsigned)H && (unsigned)gx < (unsigned)W)
        pSrc[i] = ((gy << WLOG) + gx) * Cin + part * 8;
    }
  }
  int bLds[9], bSrc[9];
#pragma unroll
  for (int i = 0; i < 9; i++) {
    int sidx = tid + i * 256;
    int n = sidx / 36, c16 = sidx - n * 36;
    bLds[i] = n * 296 + c16 * 8;
    bSrc[i] = (co0 + n) * Kp + c16 * 8;
  }

  floatx4 zero = {0.f, 0.f, 0.f, 0.f};
  floatx4 acc[2][4];
#pragma unroll
  for (int mi = 0; mi < 2; mi++)
#pragma unroll
    for (int s = 0; s < 4; s++) acc[mi][s] = zero;

  const int mA0 = wave * 32 + l15;
  const int mA1 = mA0 + 16;
  const int aBase0 = ((mA0 >> WLOG) * PC + (mA0 & (W - 1))) * 40 + q * 8;
  const int aBase1 = ((mA1 >> WLOG) * PC + (mA1 & (W - 1))) * 40 + q * 8;
  const int bBase = l15 * 296 + q * 8;

  const int nGroups = Cin >> 5;
  for (int g = 0; g < nGroups; g++) {
    __syncthreads();
    {
      const int gci = g << 5;
#pragma unroll
      for (int i = 0; i < 5; i++) {
        if (pLds[i] >= 0) {
          uint4 v = {0u, 0u, 0u, 0u};
          if (pSrc[i] >= 0) v = *(const uint4*)(xb + pSrc[i] + gci);
          *(uint4*)(sm + pLds[i]) = v;
        }
      }
      const int gw = g * 288;
#pragma unroll
      for (int i = 0; i < 9; i++)
        *(uint4*)(Bw + bLds[i]) = *(const uint4*)(wT + bSrc[i] + gw);
    }
    __syncthreads();
#pragma unroll
    for (int kt = 0; kt < 9; kt++) {
      const int ky = kt / 3, kx = kt - (kt / 3) * 3;
      const int ao = (ky * PC + kx) * 40;
      bf16x8 a0 = *(const bf16x8*)(sm + aBase0 + ao);
      bf16x8 a1 = *(const bf16x8*)(sm + aBase1 + ao);
      const int bo = bBase + kt * 32;
#pragma unroll
      for (int s = 0; s < 4; s++) {
        bf16x8 bb = *(const bf16x8*)(Bw + bo + s * (16 * 296));
        acc[0][s] = __builtin_amdgcn_mfma_f32_16x16x32_bf16(a0, bb, acc[0][s], 0, 0, 0);
        acc[1][s] = __builtin_amdgcn_mfma_f32_16x16x32_bf16(a1, bb, acc[1][s], 0, 0, 0);
      }
    }
  }

#pragma unroll
  for (int s = 0; s < 4; s++) {
    const int co = co0 + s * 16 + l15;
    const float dm = dmod[b * 512 + co];
    const float bv = bias[co];
    const float sn = sNext ? sNext[b * 512 + co] : 0.f;
#pragma unroll
    for (int mi = 0; mi < 2; mi++) {
#pragma unroll
      for (int r = 0; r < 4; r++) {
        const int mloc = wave * 32 + mi * 16 + q * 4 + r;
        const int py = y0 + (mloc >> WLOG);
        const int px = mloc & (W - 1);
        const size_t oidx = (((size_t)b * H + py) * W + px) * Cout + co;
        const float v = acc[mi][s][r] * dm + bv;
        if (outF) outF[oidx] = v;
        if (outBf) outBf[oidx] = f2bf(v * sn);
      }
    }
  }
}

// ---------------- split-K fp32 3x3 modulated conv (4x4 / 8x8 layers) ----------------
template<int PIX>
__global__ __launch_bounds__(256) void modconv_splitk_kernel(
    const float* __restrict__ x, size_t xBStride, int H, int W, int Cin, int cinShift,
    int Cout, int ciChunkLog,
    const float* __restrict__ w, const float* __restrict__ s,
    float* __restrict__ partial)
{
  extern __shared__ float lds[];
  const int COLS = PIX + 2;
  const int tid = threadIdx.x;
  const int nthr = blockDim.x;
  const int b = blockIdx.y;
  const int z = blockIdx.z;
  const int nci = 1 << ciChunkLog;
  const int ci0 = z << ciChunkLog;
  const int wb = W / PIX;
  const int row = blockIdx.x / wb;
  const int x0 = (blockIdx.x % wb) * PIX;

  const float* xb = x + (size_t)b * xBStride;
  const float* sv = s + b * 512;

  const int tot = 3 * COLS << ciChunkLog;
  for (int idx = tid; idx < tot; idx += nthr) {
    int cil = idx & (nci - 1);
    int t = idx >> ciChunkLog;
    int col = t % COLS;
    int ry = t / COLS;
    int gy = row + ry - 1;
    int gx = x0 + col - 1;
    float v = 0.f;
    if (gy >= 0 && gy < H && gx >= 0 && gx < W)
      v = xb[((size_t)(gy * W + gx) << cinShift) + ci0 + cil] * sv[ci0 + cil];
    lds[idx] = v;
  }
  __syncthreads();

  float acc0[PIX];
  float acc1[PIX];
#pragma unroll
  for (int p = 0; p < PIX; p++) { acc0[p] = 0.f; acc1[p] = 0.f; }
  const int co0 = tid;
  const int co1 = tid + nthr;
  const bool a0 = co0 < Cout;
  const bool a1 = co1 < Cout;

  const float4* ldsv = (const float4*)lds;
  const int cin4Shift = ciChunkLog - 2;

  for (int kt = 0; kt < 9; kt++) {
    int ky = kt / 3, kx = kt % 3;
    const float* wr = w + ((size_t)(kt << cinShift) + ci0) * Cout + co0;
    for (int c4 = 0; c4 < (nci >> 2); c4++) {
      float wA0 = 0.f, wA1 = 0.f, wA2 = 0.f, wA3 = 0.f;
      float wB0 = 0.f, wB1 = 0.f, wB2 = 0.f, wB3 = 0.f;
      int d01 = co1 - co0;
      if (a0) { wA0 = wr[0]; }
      if (a1) { wB0 = wr[d01]; }
      wr += Cout;
      if (a0) { wA1 = wr[0]; }
      if (a1) { wB1 = wr[d01]; }
      wr += Cout;
      if (a0) { wA2 = wr[0]; }
      if (a1) { wB2 = wr[d01]; }
      wr += Cout;
      if (a0) { wA3 = wr[0]; }
      if (a1) { wB3 = wr[d01]; }
      wr += Cout;
#pragma unroll
      for (int p = 0; p < PIX; p++) {
        float4 v = ldsv[((ky * COLS + kx + p) << cin4Shift) + c4];
        acc0[p] += v.x * wA0; acc0[p] += v.y * wA1; acc0[p] += v.z * wA2; acc0[p] += v.w * wA3;
        acc1[p] += v.x * wB0; acc1[p] += v.y * wB1; acc1[p] += v.z * wB2; acc1[p] += v.w * wB3;
      }
    }
  }

  const int HW = H * W;
  float* pb = partial + ((size_t)(z * gridDim.y + b) * HW + row * W + x0) * Cout;
#pragma unroll
  for (int p = 0; p < PIX; p++) {
    if (a0) pb[(size_t)p * Cout + co0] = acc0[p];
    if (a1) pb[(size_t)p * Cout + co1] = acc1[p];
  }
}

// ---------------- splitk epilogue ----------------
__global__ __launch_bounds__(256) void splitk_epi_kernel(
    const float* __restrict__ partial, int nz, int M, int Cout, int HW,
    const float* __restrict__ dmod, const float* __restrict__ bias,
    const float* __restrict__ noise, const float* __restrict__ ns,
    float* __restrict__ out, int doAct)
{
  int idx = blockIdx.x * 256 + threadIdx.x;
  if (idx >= M * Cout) return;
  int m = idx / Cout;
  int co = idx - m * Cout;
  int b = m / HW;
  float acc = 0.f;
  for (int z = 0; z < nz; z++) acc += partial[(size_t)z * M * Cout + idx];
  float v = acc * dmod[b * 512 + co] + bias[co];
  if (noise) v += ns[0] * noise[m];
  if (doAct) v = LEAKY(v);
  out[idx] = v;
}

// ---------------- to_rgb ----------------
__global__ __launch_bounds__(64) void rgb_kernel(
    const float* __restrict__ y, int H, int W, int Cin,
    const float* __restrict__ w, const float* __restrict__ bias,
    const float* __restrict__ s, const float* __restrict__ prev,
    float* __restrict__ out)
{
  int b = blockIdx.y;
  int pix = blockIdx.x;
  int oy = pix / W, ox = pix % W;
  const float* xp = y + (((size_t)b * H + oy) * W + ox) * Cin;
  const float* sv = s + b * 512;
  float p0 = 0.f, p1 = 0.f, p2 = 0.f;
  for (int ci = threadIdx.x; ci < Cin; ci += 64) {
    float v = xp[ci] * sv[ci];
    p0 += v * w[ci * 3 + 0];
    p1 += v * w[ci * 3 + 1];
    p2 += v * w[ci * 3 + 2];
  }
  for (int off = 32; off > 0; off >>= 1) {
    p0 += __shfl_down(p0, off);
    p1 += __shfl_down(p1, off);
    p2 += __shfl_down(p2, off);
  }
  if (threadIdx.x == 0) {
    float r0 = p0 + bias[0], r1 = p1 + bias[1], r2 = p2 + bias[2];
    float sk0 = 0.f, sk1 = 0.f, sk2 = 0.f;
    if (prev) {
      int Hp = H >> 1, Wp = W >> 1;
      int ry0, ry1, rx0, rx1; float wy0, wy1, wx0, wx1;
      blur_taps(oy, &ry0, &ry1, &wy0, &wy1);
      blur_taps(ox, &rx0, &rx1, &wx0, &wx1);
      bool vy0 = (ry0 >= 0 && ry0 < Hp), vy1 = (ry1 >= 0 && ry1 < Hp);
      bool vx0 = (rx0 >= 0 && rx0 < Wp), vx1 = (rx1 >= 0 && rx1 < Wp);
      const float* base = prev + (size_t)b * Hp * Wp * 3;
      float a0 = 0.f, a1 = 0.f, a2 = 0.f;
      if (vy0 && vx0) { const float* qq = base + (size_t)(ry0 * Wp + rx0) * 3; float wg = wy0 * wx0; a0 += wg * qq[0]; a1 += wg * qq[1]; a2 += wg * qq[2]; }
      if (vy0 && vx1) { const float* qq = base + (size_t)(ry0 * Wp + rx1) * 3; float wg = wy0 * wx1; a0 += wg * qq[0]; a1 += wg * qq[1]; a2 += wg * qq[2]; }
      if (vy1 && vx0) { const float* qq = base + (size_t)(ry1 * Wp + rx0) * 3; float wg = wy1 * wx0; a0 += wg * qq[0]; a1 += wg * qq[1]; a2 += wg * qq[2]; }
      if (vy1 && vx1) { const float* qq = base + (size_t)(ry1 * Wp + rx1) * 3; float wg = wy1 * wx1; a0 += wg * qq[0]; a1 += wg * qq[1]; a2 += wg * qq[2]; }
      sk0 = a0 * (1.f / 16.f); sk1 = a1 * (1.f / 16.f); sk2 = a2 * (1.f / 16.f);
    }
    float* ob = out + (((size_t)b * H + oy) * W + ox) * 3;
    ob[0] = LEAKY(r0) + sk0;
    ob[1] = LEAKY(r1) + sk1;
    ob[2] = LEAKY(r2) + sk2;
  }
}

extern "C" void kernel_launch(void* const* d_in, const int* in_sizes, int n_in,
                              void* d_out, int out_size, void* d_ws, size_t ws_size,
                              hipStream_t stream)
{
  auto F = [&](int k) { return (const float*)d_in[k]; };
  const float* latents = F(0);
  const float* cnst = F(1);
  const float* w0 = F(2);  const float* b0 = F(3);  const float* sw0 = F(4);  const float* sb0 = F(5);
  const float* ns0 = F(6); const float* noise0 = F(7);
  const float* wr0 = F(8); const float* br0 = F(9); const float* swr0 = F(10); const float* sbr0 = F(11);
  const float *wu[4], *bu[4], *swu[4], *sbu[4];
  const float *wc[4], *bc[4], *swc[4], *sbc[4];
  const float *wr[4], *br_[4], *swr[4], *sbr[4];
  int k = 12;
  for (int l = 0; l < 4; l++) {
    wu[l] = F(k++); bu[l] = F(k++); swu[l] = F(k++); sbu[l] = F(k++);
    wc[l] = F(k++); bc[l] = F(k++); swc[l] = F(k++); sbc[l] = F(k++);
    wr[l] = F(k++); br_[l] = F(k++); swr[l] = F(k++); sbr[l] = F(k++);
  }

  // ---- workspace layout ----
  float* ws = (float*)d_ws;
  float* S = ws;                              // 14*1024
  float* D = S + 14 * 1024;                   // 9*1024
  float* W2 = D + 9 * 1024;                   // 1,359,872 floats
  float* bufA = W2 + 1359872;                 // 2*64*64*512
  float* bufB = bufA + 2 * 64 * 64 * 512;
  float* rgbA = bufB + 2 * 64 * 64 * 512;
  float* rgbB = rgbA + 2 * 64 * 64 * 3;
  float* P = rgbB + 2 * 64 * 64 * 3;          // split-K partials: 131072 floats
  unsigned short* u16 = (unsigned short*)(P + 131072);
  unsigned short* xprepA = u16;
  unsigned short* xprepB = xprepA + 2 * 64 * 64 * 512;
  unsigned short* wT[6];
  {
    unsigned short* p = xprepB + 2 * 64 * 64 * 512;
    int wsz[6] = {9 * 128 * 256, 9 * 256 * 256, 9 * 256 * 512, 9 * 512 * 512, 9 * 512 * 512, 9 * 512 * 512};
    for (int i = 0; i < 6; i++) { wT[i] = p; p += wsz[i]; }
  }

  const int B = 2;
  const int NFa[5] = {64, 128, 256, 512, 512};
  int cprev0[4] = {512, 128, 256, 512};
  int rowu[4] = {1, 6, 6, 6};

  // conv enumeration (shared by W2 / demod2): cin/cout logs
  const float* cw[9]  = {w0, wu[0], wc[0], wu[1], wc[1], wu[2], wc[2], wu[3], wc[3]};
  int cinL[9]  = {9, 9, 7, 7, 8, 8, 9, 9, 9};   // 512,512,128,128,256,256,512,512,512
  int coutL[9] = {9, 7, 7, 8, 8, 9, 9, 9, 9};   // 512,128,128,256,256,512,512,512,512
  int sidOf[9] = {0, 2, 3, 5, 6, 8, 9, 11, 12};
  int didOf[9] = {0, 1, 2, 3, 4, 5, 6, 7, 8};

  // ---- fused weight prep (6 mfma convs) ----
  {
    WPArgs WA;
    const float* srcs[6] = {wu[1], wc[1], wu[2], wc[2], wu[3], wc[3]};
    int cins[6] = {128, 256, 256, 512, 512, 512};
    int couts[6] = {256, 256, 512, 512, 512, 512};
    int start = 0;
    for (int i = 0; i < 6; i++) {
      WA.d[i] = {srcs[i], wT[i], cins[i], couts[i], start};
      start += couts[i] * cins[i] * 9 / 8;
    }
    WA.total = start;
    wprep_kernel<<<dim3((start + 255) / 256), 256, 0, stream>>>(WA);
  }

  // ---- fused styles (14) ----
  {
    StyleArgs SA;
    SA.d[0] = {sw0, sb0, 0, 512};
    SA.d[1] = {swr0, sbr0, 1, 512};
    for (int l = 0; l < 4; l++) {
      int c = NFa[l + 1];
      SA.d[2 + l * 3] = {swu[l], sbu[l], rowu[l], cprev0[l]};
      SA.d[3 + l * 3] = {swc[l], sbc[l], 5, c};
      SA.d[4 + l * 3] = {swr[l], sbr[l], 6, c};
    }
    style_all_kernel<<<dim3(56), 256, 0, stream>>>(latents, SA, S);
  }

  // ---- W2 (batch-independent, one dispatch, float4/thread) ----
  int w2off[9];
  {
    W2Args WA2;
    int start = 0, off = 0;
    for (int i = 0; i < 9; i++) {
      w2off[i] = off;
      WA2.d[i] = {cw[i], cinL[i], coutL[i], start, off};
      int elems = 1 << (cinL[i] + coutL[i]);
      start += elems >> 2;
      off += elems;
    }
    WA2.total4 = start;
    w2_kernel<<<dim3((start + 255) / 256), 256, 0, stream>>>(WA2, W2);
  }

  // ---- demod2 (small matvec over Cin) ----
  {
    D2Args DA;
    int start = 0;
    for (int i = 0; i < 9; i++) {
      int cout = 1 << coutL[i];
      DA.d[i] = {w2off[i], sidOf[i], didOf[i], 1 << cinL[i], cout, start};
      start += B * (cout >> 6);
    }
    demod2_all_kernel<<<dim3(start), 256, 0, stream>>>(DA, W2, S, D);
  }

  // ---- conv0 (4x4, fp32 split-K z=8) + epi + rgb0 ----
  modconv_splitk_kernel<4><<<dim3(4, B, 8), 256, (size_t)3 * 6 * 64 * 4, stream>>>(
      cnst, 0, 4, 4, 512, 9, 512, 6, w0, S, P);
  splitk_epi_kernel<<<dim3((32 * 512 + 255) / 256), 256, 0, stream>>>(
      P, 8, 32, 512, 16, D, b0, noise0, ns0, bufA, 1);
  rgb_kernel<<<dim3(16, B), 64, 0, stream>>>(bufA, 4, 4, 512, wr0, br0, S + 1024, nullptr, rgbA);

  // ---- level 1 (8x8, fp32 split-K) ----
  blur_up_kernel<<<dim3(64, B), 256, 0, stream>>>(bufA, 4, 4, 512, bufB);
  modconv_splitk_kernel<8><<<dim3(8, B, 8), 128, (size_t)3 * 10 * 64 * 4, stream>>>(
      bufB, (size_t)64 * 512, 8, 8, 512, 9, 128, 6, wu[0], S + 2 * 1024, P);
  splitk_epi_kernel<<<dim3((128 * 128 + 255) / 256), 256, 0, stream>>>(
      P, 8, 128, 128, 64, D + 1 * 1024, bu[0], nullptr, nullptr, bufA, 0);
  modconv_splitk_kernel<8><<<dim3(8, B, 4), 128, (size_t)3 * 10 * 32 * 4, stream>>>(
      bufA, (size_t)64 * 128, 8, 8, 128, 7, 128, 5, wc[0], S + 3 * 1024, P);
  splitk_epi_kernel<<<dim3((128 * 128 + 255) / 256), 256, 0, stream>>>(
      P, 4, 128, 128, 64, D + 2 * 1024, bc[0], nullptr, nullptr, bufB, 0);
  rgb_kernel<<<dim3(64, B), 64, 0, stream>>>(bufB, 8, 8, 128, wr[0], br_[0], S + 4 * 1024, rgbA, rgbB);

  // ---- levels 2..4 (MFMA path) ----
  float* ybuf[4] = {bufB, bufA, bufB, bufA};
  float* rgbp = rgbB;
  const float* ysrc = bufB;
  int Hc = 8;
  for (int l = 1; l < 4; l++) {
    int c = NFa[l + 1];
    int cp = cprev0[l];
    int H2 = Hc * 2;
    int WLOG = (H2 == 16) ? 4 : (H2 == 32) ? 5 : 6;
    int wi = (l - 1) * 2;
    prep_up_kernel<<<dim3(H2 * H2, B), 256, 0, stream>>>(
        ysrc, Hc, cp, S + (2 + l * 3) * 1024, xprepA);
    {
      int PRu = (128 >> WLOG) + 2, PCu = H2 + 2;
      size_t lds = (size_t)(PRu * PCu * 40 + 64 * 296) * 2;
      mfma_conv_kernel<<<dim3((B * H2 * H2) / 128, c >> 6), 256, lds, stream>>>(
          xprepA, H2, WLOG, cp, c, wT[wi], bu[l], D + (1 + l * 2) * 1024,
          nullptr, xprepB, S + (3 + l * 3) * 1024);
    }
    float* yo = ybuf[l];
    {
      int PRu = (128 >> WLOG) + 2, PCu = H2 + 2;
      size_t lds = (size_t)(PRu * PCu * 40 + 64 * 296) * 2;
      mfma_conv_kernel<<<dim3((B * H2 * H2) / 128, c >> 6), 256, lds, stream>>>(
          xprepB, H2, WLOG, c, c, wT[wi + 1], bc[l], D + (2 + l * 2) * 1024,
          yo, nullptr, nullptr);
    }
    float* rout = (l == 3) ? (float*)d_out : ((rgbp == rgbA) ? rgbB : rgbA);
    rgb_kernel<<<dim3(H2 * H2, B), 64, 0, stream>>>(
        yo, H2, H2, c, wr[l], br_[l], S + (4 + l * 3) * 1024, rgbp, rout);
    rgbp = (rout == rgbA) ? rgbA : rgbB;
    ysrc = yo;
    Hc = H2;
  }
  (void)in_sizes; (void)n_in; (void)out_size; (void)ws_size;
}

// Round 6
// 625.734 us; speedup vs baseline: 45.6789x; 1.2035x over previous
//
#include <hip/hip_runtime.h>

#define LEAKY(v) ((v) > 0.f ? (v) : 0.01f * (v))

typedef __attribute__((ext_vector_type(8))) short bf16x8;
typedef __attribute__((ext_vector_type(4))) float floatx4;

__device__ inline unsigned short f2bf(float f) {
  unsigned u = __float_as_uint(f);
  unsigned r = u + 0x7FFFu + ((u >> 16) & 1u);
  return (unsigned short)(r >> 16);
}

// ---------------- fused style: all 14 affines in one dispatch ----------------
struct StyleDesc { const float* sw; const float* sb; int row; int cin; };
struct StyleArgs { StyleDesc d[14]; };

__global__ __launch_bounds__(256) void style_all_kernel(
    const float* __restrict__ lat, StyleArgs A, float* __restrict__ S)
{
  int bid = blockIdx.x;
  int chunk = bid & 1, b = (bid >> 1) & 1, sid = bid >> 2;
  StyleDesc d = A.d[sid];
  int ci = chunk * 256 + threadIdx.x;
  if (ci >= d.cin) return;
  const float* l = lat + (size_t)b * (10 * 512) + d.row * 512;
  float a0 = 0.f, a1 = 0.f, a2 = 0.f, a3 = 0.f, a4 = 0.f, a5 = 0.f, a6 = 0.f, a7 = 0.f;
  const float* wp = d.sw + ci;
  size_t st = d.cin;
  for (int k = 0; k < 512; k += 8) {
    a0 += l[k] * wp[0];
    a1 += l[k + 1] * wp[st];
    a2 += l[k + 2] * wp[2 * st];
    a3 += l[k + 3] * wp[3 * st];
    a4 += l[k + 4] * wp[4 * st];
    a5 += l[k + 5] * wp[5 * st];
    a6 += l[k + 6] * wp[6 * st];
    a7 += l[k + 7] * wp[7 * st];
    wp += 8 * st;
  }
  S[sid * 1024 + b * 512 + ci] = d.sb[ci] + ((a0 + a1) + (a2 + a3)) + ((a4 + a5) + (a6 + a7));
}

// ---------------- W2[ci][co] = sum_kt w[kt][ci][co]^2 ----------------
struct W2D { const float* w; int cinLog; int coutLog; int start; int w2off; };
struct W2Args { W2D d[9]; int total4; };

__global__ __launch_bounds__(256) void w2_kernel(W2Args A, float* __restrict__ W2)
{
  int idx = blockIdx.x * 256 + threadIdx.x;
  if (idx >= A.total4) return;
  int c = 0;
  while (c < 8 && idx >= A.d[c + 1].start) c++;
  W2D d = A.d[c];
  int rel = idx - d.start;
  int co4Log = d.coutLog - 2;
  int ci = rel >> co4Log;
  int co = (rel & ((1 << co4Log) - 1)) << 2;
  size_t ktStride = (size_t)(1 << d.cinLog) << d.coutLog;
  const float* p = d.w + ((size_t)ci << d.coutLog) + co;
  float4 acc = {0.f, 0.f, 0.f, 0.f};
#pragma unroll
  for (int kt = 0; kt < 9; kt++) {
    float4 v = *(const float4*)(p + kt * ktStride);
    acc.x += v.x * v.x; acc.y += v.y * v.y; acc.z += v.z * v.z; acc.w += v.w * v.w;
  }
  *(float4*)(W2 + d.w2off + ((size_t)ci << d.coutLog) + co) = acc;
}

// ---------------- demod2 ----------------
struct D2D { int w2off; int sid; int did; int cin; int cout; int start; };
struct D2Args { D2D d[9]; };

__global__ __launch_bounds__(256) void demod2_all_kernel(
    D2Args A, const float* __restrict__ W2, const float* __restrict__ S,
    float* __restrict__ Dout)
{
  __shared__ float red[256];
  int bid = blockIdx.x;
  int c = 0;
  while (c < 8 && bid >= A.d[c + 1].start) c++;
  D2D d = A.d[c];
  int rel = bid - d.start;
  int chunksPerB = d.cout >> 6;
  int b = rel / chunksPerB;
  int coc = rel - b * chunksPerB;
  int co = coc * 64 + (threadIdx.x & 63);
  int slice = threadIdx.x >> 6;
  const float* sv = S + d.sid * 1024 + b * 512;
  const float* wp = W2 + d.w2off + co;
  float a0 = 0.f, a1 = 0.f, a2 = 0.f, a3 = 0.f, a4 = 0.f, a5 = 0.f, a6 = 0.f, a7 = 0.f;
  for (int r = slice; r < d.cin; r += 32) {
    float s0 = sv[r];          a0 += s0 * s0 * wp[(size_t)r * d.cout];
    float s1 = sv[r + 4];      a1 += s1 * s1 * wp[(size_t)(r + 4) * d.cout];
    float s2 = sv[r + 8];      a2 += s2 * s2 * wp[(size_t)(r + 8) * d.cout];
    float s3 = sv[r + 12];     a3 += s3 * s3 * wp[(size_t)(r + 12) * d.cout];
    float s4 = sv[r + 16];     a4 += s4 * s4 * wp[(size_t)(r + 16) * d.cout];
    float s5 = sv[r + 20];     a5 += s5 * s5 * wp[(size_t)(r + 20) * d.cout];
    float s6 = sv[r + 24];     a6 += s6 * s6 * wp[(size_t)(r + 24) * d.cout];
    float s7 = sv[r + 28];     a7 += s7 * s7 * wp[(size_t)(r + 28) * d.cout];
  }
  red[threadIdx.x] = ((a0 + a1) + (a2 + a3)) + ((a4 + a5) + (a6 + a7));
  __syncthreads();
  if (threadIdx.x < 64) {
    float a = red[threadIdx.x] + red[threadIdx.x + 64] + red[threadIdx.x + 128] + red[threadIdx.x + 192];
    Dout[d.did * 1024 + b * 512 + co] = rsqrtf(a + 1e-8f);
  }
}

// ---------------- fused weight prep: fp32 [kt][ci][co] -> bf16 [co][k'] ----------------
struct WPD { const float* src; unsigned short* dst; int cin; int cout; int start; };
struct WPArgs { WPD d[6]; int total; };

__global__ __launch_bounds__(256) void wprep_kernel(WPArgs A)
{
  int chunk = blockIdx.x * 256 + threadIdx.x;
  if (chunk >= A.total) return;
  int c = 0;
  while (c < 5 && chunk >= A.d[c + 1].start) c++;
  WPD d = A.d[c];
  int rel = chunk - d.start;
  int cpc = d.cin * 9 / 8;
  int co = rel / cpc;
  int k0 = (rel - co * cpc) * 8;
  int cig = k0 / 288;
  int r = k0 - cig * 288;
  int kt = r >> 5;
  int cibase = cig * 32 + (r & 31);
  const float* sp = d.src + (size_t)(kt * d.cin + cibase) * d.cout + co;
  size_t st = d.cout;
  unsigned r0 = f2bf(sp[0]) | ((unsigned)f2bf(sp[st]) << 16);
  unsigned r1 = f2bf(sp[2 * st]) | ((unsigned)f2bf(sp[3 * st]) << 16);
  unsigned r2 = f2bf(sp[4 * st]) | ((unsigned)f2bf(sp[5 * st]) << 16);
  unsigned r3 = f2bf(sp[6 * st]) | ((unsigned)f2bf(sp[7 * st]) << 16);
  uint4 v = {r0, r1, r2, r3};
  *(uint4*)(d.dst + (size_t)co * (d.cin * 9) + k0) = v;
}

// ---------------- blur_up taps ----------------
__device__ inline void blur_taps(int o, int* r0, int* r1, float* w0, float* w1)
{
  if ((o & 1) == 0) { *r0 = (o >> 1) - 1; *w0 = 1.f; *r1 = (o >> 1); *w1 = 3.f; }
  else              { *r0 = (o - 1) >> 1; *w0 = 3.f; *r1 = ((o - 1) >> 1) + 1; *w1 = 1.f; }
}

__global__ __launch_bounds__(256) void blur_up_kernel(
    const float* __restrict__ x, int H, int W, int C, float* __restrict__ out)
{
  int b = blockIdx.y;
  int W2 = W * 2;
  int pix = blockIdx.x;
  int oy = pix / W2, ox = pix % W2;
  int ry0, ry1, rx0, rx1; float wy0, wy1, wx0, wx1;
  blur_taps(oy, &ry0, &ry1, &wy0, &wy1);
  blur_taps(ox, &rx0, &rx1, &wx0, &wx1);
  bool vy0 = (ry0 >= 0 && ry0 < H), vy1 = (ry1 >= 0 && ry1 < H);
  bool vx0 = (rx0 >= 0 && rx0 < W), vx1 = (rx1 >= 0 && rx1 < W);
  const float* base = x + (size_t)b * H * W * C;
  float* ob = out + (((size_t)b * W2 + oy) * W2 + ox) * C;
  for (int c = threadIdx.x; c < C; c += 256) {
    float acc = 0.f;
    if (vy0) {
      const float* r = base + (size_t)(ry0 * W) * C;
      if (vx0) acc += wy0 * wx0 * r[(size_t)rx0 * C + c];
      if (vx1) acc += wy0 * wx1 * r[(size_t)rx1 * C + c];
    }
    if (vy1) {
      const float* r = base + (size_t)(ry1 * W) * C;
      if (vx0) acc += wy1 * wx0 * r[(size_t)rx0 * C + c];
      if (vx1) acc += wy1 * wx1 * r[(size_t)rx1 * C + c];
    }
    ob[c] = acc * (1.f / 16.f);
  }
}

// ---------------- prep_up: blur_up + style fold + bf16 cast ----------------
__global__ __launch_bounds__(256) void prep_up_kernel(
    const float* __restrict__ y, int Hc, int C,
    const float* __restrict__ s, unsigned short* __restrict__ out)
{
  int b = blockIdx.y;
  int W2 = Hc * 2;
  int pix = blockIdx.x;
  int oy = pix / W2, ox = pix - oy * W2;
  int ry0, ry1, rx0, rx1; float wy0, wy1, wx0, wx1;
  blur_taps(oy, &ry0, &ry1, &wy0, &wy1);
  blur_taps(ox, &rx0, &rx1, &wx0, &wx1);
  bool vy0 = (ry0 >= 0 && ry0 < Hc), vy1 = (ry1 >= 0 && ry1 < Hc);
  bool vx0 = (rx0 >= 0 && rx0 < Hc), vx1 = (rx1 >= 0 && rx1 < Hc);
  const float* base = y + (size_t)b * Hc * Hc * C;
  unsigned short* ob = out + (((size_t)b * W2 + oy) * W2 + ox) * C;
  const float* sv = s + b * 512;
  for (int c = threadIdx.x; c < C; c += 256) {
    float acc = 0.f;
    if (vy0) {
      const float* r = base + (size_t)(ry0 * Hc) * C;
      if (vx0) acc += wy0 * wx0 * r[(size_t)rx0 * C + c];
      if (vx1) acc += wy0 * wx1 * r[(size_t)rx1 * C + c];
    }
    if (vy1) {
      const float* r = base + (size_t)(ry1 * Hc) * C;
      if (vx0) acc += wy1 * wx0 * r[(size_t)rx0 * C + c];
      if (vx1) acc += wy1 * wx1 * r[(size_t)rx1 * C + c];
    }
    ob[c] = f2bf(acc * (1.f / 16.f) * sv[c]);
  }
}

// ---------------- MFMA implicit-GEMM 3x3 conv (levels 2..4) ----------------
__global__ __launch_bounds__(256) void mfma_conv_kernel(
    const unsigned short* __restrict__ xp, int H, int WLOG, int Cin, int Cout,
    const unsigned short* __restrict__ wT,
    const float* __restrict__ bias, const float* __restrict__ dmod,
    float* __restrict__ outF, unsigned short* __restrict__ outBf,
    const float* __restrict__ sNext)
{
  extern __shared__ unsigned short sm[];
  const int W = 1 << WLOG;
  const int Rt = 128 >> WLOG;
  const int PR = Rt + 2, PC = W + 2;
  const int patchU = PR * PC * 40;
  unsigned short* Bw = sm + patchU;

  const int tid = threadIdx.x;
  const int wave = tid >> 6;
  const int lane = tid & 63;
  const int q = lane >> 4;
  const int l15 = lane & 15;

  const int HW = H << WLOG;
  const int m0 = blockIdx.x << 7;
  const int b = m0 / HW;
  const int y0 = (m0 - b * HW) >> WLOG;
  const int co0 = blockIdx.y << 6;
  const int Kp = Cin * 9;
  const unsigned short* xb = xp + (size_t)b * HW * Cin;

  const int pSlots = PR * PC * 4;
  int pLds[5], pSrc[5];
#pragma unroll
  for (int i = 0; i < 5; i++) {
    int sidx = tid + i * 256;
    pLds[i] = -1; pSrc[i] = -1;
    if (sidx < pSlots) {
      int pidx = sidx >> 2, part = sidx & 3;
      int pr = pidx / PC, pc = pidx - pr * PC;
      int gy = y0 + pr - 1, gx = pc - 1;
      pLds[i] = pidx * 40 + part * 8;
      if ((unsigned)gy < (unsigned)H && (unsigned)gx < (unsigned)W)
        pSrc[i] = ((gy << WLOG) + gx) * Cin + part * 8;
    }
  }
  int bLds[9], bSrc[9];
#pragma unroll
  for (int i = 0; i < 9; i++) {
    int sidx = tid + i * 256;
    int n = sidx / 36, c16 = sidx - n * 36;
    bLds[i] = n * 296 + c16 * 8;
    bSrc[i] = (co0 + n) * Kp + c16 * 8;
  }

  floatx4 zero = {0.f, 0.f, 0.f, 0.f};
  floatx4 acc[2][4];
#pragma unroll
  for (int mi = 0; mi < 2; mi++)
#pragma unroll
    for (int s = 0; s < 4; s++) acc[mi][s] = zero;

  const int mA0 = wave * 32 + l15;
  const int mA1 = mA0 + 16;
  const int aBase0 = ((mA0 >> WLOG) * PC + (mA0 & (W - 1))) * 40 + q * 8;
  const int aBase1 = ((mA1 >> WLOG) * PC + (mA1 & (W - 1))) * 40 + q * 8;
  const int bBase = l15 * 296 + q * 8;

  const int nGroups = Cin >> 5;
  for (int g = 0; g < nGroups; g++) {
    __syncthreads();
    {
      const int gci = g << 5;
#pragma unroll
      for (int i = 0; i < 5; i++) {
        if (pLds[i] >= 0) {
          uint4 v = {0u, 0u, 0u, 0u};
          if (pSrc[i] >= 0) v = *(const uint4*)(xb + pSrc[i] + gci);
          *(uint4*)(sm + pLds[i]) = v;
        }
      }
      const int gw = g * 288;
#pragma unroll
      for (int i = 0; i < 9; i++)
        *(uint4*)(Bw + bLds[i]) = *(const uint4*)(wT + bSrc[i] + gw);
    }
    __syncthreads();
#pragma unroll
    for (int kt = 0; kt < 9; kt++) {
      const int ky = kt / 3, kx = kt - (kt / 3) * 3;
      const int ao = (ky * PC + kx) * 40;
      bf16x8 a0 = *(const bf16x8*)(sm + aBase0 + ao);
      bf16x8 a1 = *(const bf16x8*)(sm + aBase1 + ao);
      const int bo = bBase + kt * 32;
#pragma unroll
      for (int s = 0; s < 4; s++) {
        bf16x8 bb = *(const bf16x8*)(Bw + bo + s * (16 * 296));
        acc[0][s] = __builtin_amdgcn_mfma_f32_16x16x32_bf16(a0, bb, acc[0][s], 0, 0, 0);
        acc[1][s] = __builtin_amdgcn_mfma_f32_16x16x32_bf16(a1, bb, acc[1][s], 0, 0, 0);
      }
    }
  }

#pragma unroll
  for (int s = 0; s < 4; s++) {
    const int co = co0 + s * 16 + l15;
    const float dm = dmod[b * 512 + co];
    const float bv = bias[co];
    const float sn = sNext ? sNext[b * 512 + co] : 0.f;
#pragma unroll
    for (int mi = 0; mi < 2; mi++) {
#pragma unroll
      for (int r = 0; r < 4; r++) {
        const int mloc = wave * 32 + mi * 16 + q * 4 + r;
        const int py = y0 + (mloc >> WLOG);
        const int px = mloc & (W - 1);
        const size_t oidx = (((size_t)b * H + py) * W + px) * Cout + co;
        const float v = acc[mi][s][r] * dm + bv;
        if (outF) outF[oidx] = v;
        if (outBf) outBf[oidx] = f2bf(v * sn);
      }
    }
  }
}

// ---------------- split-K fp32 3x3 modulated conv (4x4 / 8x8 layers) ----------------
// NCI4 compile-time -> fully-unrolled inner loop -> 32+ outstanding weight loads.
template<int PIX, int NCI4>
__global__ __launch_bounds__(256) void modconv_splitk_kernel(
    const float* __restrict__ x, size_t xBStride, int H, int W, int cinShift,
    int Cout,
    const float* __restrict__ w, const float* __restrict__ s,
    float* __restrict__ partial)
{
  constexpr int NCI = NCI4 * 4;
  constexpr int CLOG = (NCI == 16) ? 4 : (NCI == 32) ? 5 : 6;
  extern __shared__ float lds[];
  const int COLS = PIX + 2;
  const int tid = threadIdx.x;
  const int nthr = blockDim.x;
  const int b = blockIdx.y;
  const int z = blockIdx.z;
  const int ci0 = z << CLOG;
  const int wb = W / PIX;
  const int row = blockIdx.x / wb;
  const int x0 = (blockIdx.x % wb) * PIX;

  const float* xb = x + (size_t)b * xBStride;
  const float* sv = s + b * 512;

  const int tot = 3 * COLS << CLOG;
  for (int idx = tid; idx < tot; idx += nthr) {
    int cil = idx & (NCI - 1);
    int t = idx >> CLOG;
    int col = t % COLS;
    int ry = t / COLS;
    int gy = row + ry - 1;
    int gx = x0 + col - 1;
    float v = 0.f;
    if (gy >= 0 && gy < H && gx >= 0 && gx < W)
      v = xb[((size_t)(gy * W + gx) << cinShift) + ci0 + cil] * sv[ci0 + cil];
    lds[idx] = v;
  }
  __syncthreads();

  float acc0[PIX];
  float acc1[PIX];
#pragma unroll
  for (int p = 0; p < PIX; p++) { acc0[p] = 0.f; acc1[p] = 0.f; }
  const int co0 = tid;
  const int co1 = tid + nthr;
  const bool a0 = co0 < Cout;
  const bool a1 = co1 < Cout;
  const int d01 = nthr;

  const float4* ldsv = (const float4*)lds;
  constexpr int cin4Shift = CLOG - 2;

  for (int kt = 0; kt < 9; kt++) {
    int ky = kt / 3, kx = kt % 3;
    const float* wr = w + ((size_t)(kt << cinShift) + ci0) * Cout + co0;
#pragma unroll
    for (int c4 = 0; c4 < NCI4; c4++) {
      float wA0 = 0.f, wA1 = 0.f, wA2 = 0.f, wA3 = 0.f;
      float wB0 = 0.f, wB1 = 0.f, wB2 = 0.f, wB3 = 0.f;
      const float* wq = wr + (size_t)c4 * 4 * Cout;
      if (a0) { wA0 = wq[0]; }
      if (a1) { wB0 = wq[d01]; }
      if (a0) { wA1 = wq[Cout]; }
      if (a1) { wB1 = wq[Cout + d01]; }
      if (a0) { wA2 = wq[2 * Cout]; }
      if (a1) { wB2 = wq[2 * Cout + d01]; }
      if (a0) { wA3 = wq[3 * Cout]; }
      if (a1) { wB3 = wq[3 * Cout + d01]; }
#pragma unroll
      for (int p = 0; p < PIX; p++) {
        float4 v = ldsv[((ky * COLS + kx + p) << cin4Shift) + c4];
        acc0[p] += v.x * wA0; acc0[p] += v.y * wA1; acc0[p] += v.z * wA2; acc0[p] += v.w * wA3;
        acc1[p] += v.x * wB0; acc1[p] += v.y * wB1; acc1[p] += v.z * wB2; acc1[p] += v.w * wB3;
      }
    }
  }

  const int HW = H * W;
  float* pb = partial + ((size_t)(z * gridDim.y + b) * HW + row * W + x0) * Cout;
#pragma unroll
  for (int p = 0; p < PIX; p++) {
    if (a0) pb[(size_t)p * Cout + co0] = acc0[p];
    if (a1) pb[(size_t)p * Cout + co1] = acc1[p];
  }
}

// ---------------- splitk epilogue ----------------
__global__ __launch_bounds__(256) void splitk_epi_kernel(
    const float* __restrict__ partial, int nz, int M, int Cout, int HW,
    const float* __restrict__ dmod, const float* __restrict__ bias,
    const float* __restrict__ noise, const float* __restrict__ ns,
    float* __restrict__ out, int doAct)
{
  int idx = blockIdx.x * 256 + threadIdx.x;
  if (idx >= M * Cout) return;
  int m = idx / Cout;
  int co = idx - m * Cout;
  int b = m / HW;
  float acc = 0.f;
  for (int z = 0; z < nz; z++) acc += partial[(size_t)z * M * Cout + idx];
  float v = acc * dmod[b * 512 + co] + bias[co];
  if (noise) v += ns[0] * noise[m];
  if (doAct) v = LEAKY(v);
  out[idx] = v;
}

// ---------------- to_rgb ----------------
__global__ __launch_bounds__(64) void rgb_kernel(
    const float* __restrict__ y, int H, int W, int Cin,
    const float* __restrict__ w, const float* __restrict__ bias,
    const float* __restrict__ s, const float* __restrict__ prev,
    float* __restrict__ out)
{
  int b = blockIdx.y;
  int pix = blockIdx.x;
  int oy = pix / W, ox = pix % W;
  const float* xp = y + (((size_t)b * H + oy) * W + ox) * Cin;
  const float* sv = s + b * 512;
  float p0 = 0.f, p1 = 0.f, p2 = 0.f;
  for (int ci = threadIdx.x; ci < Cin; ci += 64) {
    float v = xp[ci] * sv[ci];
    p0 += v * w[ci * 3 + 0];
    p1 += v * w[ci * 3 + 1];
    p2 += v * w[ci * 3 + 2];
  }
  for (int off = 32; off > 0; off >>= 1) {
    p0 += __shfl_down(p0, off);
    p1 += __shfl_down(p1, off);
    p2 += __shfl_down(p2, off);
  }
  if (threadIdx.x == 0) {
    float r0 = p0 + bias[0], r1 = p1 + bias[1], r2 = p2 + bias[2];
    float sk0 = 0.f, sk1 = 0.f, sk2 = 0.f;
    if (prev) {
      int Hp = H >> 1, Wp = W >> 1;
      int ry0, ry1, rx0, rx1; float wy0, wy1, wx0, wx1;
      blur_taps(oy, &ry0, &ry1, &wy0, &wy1);
      blur_taps(ox, &rx0, &rx1, &wx0, &wx1);
      bool vy0 = (ry0 >= 0 && ry0 < Hp), vy1 = (ry1 >= 0 && ry1 < Hp);
      bool vx0 = (rx0 >= 0 && rx0 < Wp), vx1 = (rx1 >= 0 && rx1 < Wp);
      const float* base = prev + (size_t)b * Hp * Wp * 3;
      float a0 = 0.f, a1 = 0.f, a2 = 0.f;
      if (vy0 && vx0) { const float* qq = base + (size_t)(ry0 * Wp + rx0) * 3; float wg = wy0 * wx0; a0 += wg * qq[0]; a1 += wg * qq[1]; a2 += wg * qq[2]; }
      if (vy0 && vx1) { const float* qq = base + (size_t)(ry0 * Wp + rx1) * 3; float wg = wy0 * wx1; a0 += wg * qq[0]; a1 += wg * qq[1]; a2 += wg * qq[2]; }
      if (vy1 && vx0) { const float* qq = base + (size_t)(ry1 * Wp + rx0) * 3; float wg = wy1 * wx0; a0 += wg * qq[0]; a1 += wg * qq[1]; a2 += wg * qq[2]; }
      if (vy1 && vx1) { const float* qq = base + (size_t)(ry1 * Wp + rx1) * 3; float wg = wy1 * wx1; a0 += wg * qq[0]; a1 += wg * qq[1]; a2 += wg * qq[2]; }
      sk0 = a0 * (1.f / 16.f); sk1 = a1 * (1.f / 16.f); sk2 = a2 * (1.f / 16.f);
    }
    float* ob = out + (((size_t)b * H + oy) * W + ox) * 3;
    ob[0] = LEAKY(r0) + sk0;
    ob[1] = LEAKY(r1) + sk1;
    ob[2] = LEAKY(r2) + sk2;
  }
}

extern "C" void kernel_launch(void* const* d_in, const int* in_sizes, int n_in,
                              void* d_out, int out_size, void* d_ws, size_t ws_size,
                              hipStream_t stream)
{
  auto F = [&](int k) { return (const float*)d_in[k]; };
  const float* latents = F(0);
  const float* cnst = F(1);
  const float* w0 = F(2);  const float* b0 = F(3);  const float* sw0 = F(4);  const float* sb0 = F(5);
  const float* ns0 = F(6); const float* noise0 = F(7);
  const float* wr0 = F(8); const float* br0 = F(9); const float* swr0 = F(10); const float* sbr0 = F(11);
  const float *wu[4], *bu[4], *swu[4], *sbu[4];
  const float *wc[4], *bc[4], *swc[4], *sbc[4];
  const float *wr[4], *br_[4], *swr[4], *sbr[4];
  int k = 12;
  for (int l = 0; l < 4; l++) {
    wu[l] = F(k++); bu[l] = F(k++); swu[l] = F(k++); sbu[l] = F(k++);
    wc[l] = F(k++); bc[l] = F(k++); swc[l] = F(k++); sbc[l] = F(k++);
    wr[l] = F(k++); br_[l] = F(k++); swr[l] = F(k++); sbr[l] = F(k++);
  }

  // ---- workspace layout ----
  float* ws = (float*)d_ws;
  float* S = ws;                              // 14*1024
  float* D = S + 14 * 1024;                   // 9*1024
  float* W2 = D + 9 * 1024;                   // 1,359,872 floats
  float* bufA = W2 + 1359872;                 // 2*64*64*512
  float* bufB = bufA + 2 * 64 * 64 * 512;
  float* rgbA = bufB + 2 * 64 * 64 * 512;
  float* rgbB = rgbA + 2 * 64 * 64 * 3;
  float* P = rgbB + 2 * 64 * 64 * 3;          // split-K partials: 262144 floats
  unsigned short* u16 = (unsigned short*)(P + 262144);
  unsigned short* xprepA = u16;
  unsigned short* xprepB = xprepA + 2 * 64 * 64 * 512;
  unsigned short* wT[6];
  {
    unsigned short* p = xprepB + 2 * 64 * 64 * 512;
    int wsz[6] = {9 * 128 * 256, 9 * 256 * 256, 9 * 256 * 512, 9 * 512 * 512, 9 * 512 * 512, 9 * 512 * 512};
    for (int i = 0; i < 6; i++) { wT[i] = p; p += wsz[i]; }
  }

  const int B = 2;
  const int NFa[5] = {64, 128, 256, 512, 512};
  int cprev0[4] = {512, 128, 256, 512};
  int rowu[4] = {1, 6, 6, 6};

  const float* cw[9]  = {w0, wu[0], wc[0], wu[1], wc[1], wu[2], wc[2], wu[3], wc[3]};
  int cinL[9]  = {9, 9, 7, 7, 8, 8, 9, 9, 9};
  int coutL[9] = {9, 7, 7, 8, 8, 9, 9, 9, 9};
  int sidOf[9] = {0, 2, 3, 5, 6, 8, 9, 11, 12};
  int didOf[9] = {0, 1, 2, 3, 4, 5, 6, 7, 8};

  // ---- fused weight prep (6 mfma convs) ----
  {
    WPArgs WA;
    const float* srcs[6] = {wu[1], wc[1], wu[2], wc[2], wu[3], wc[3]};
    int cins[6] = {128, 256, 256, 512, 512, 512};
    int couts[6] = {256, 256, 512, 512, 512, 512};
    int start = 0;
    for (int i = 0; i < 6; i++) {
      WA.d[i] = {srcs[i], wT[i], cins[i], couts[i], start};
      start += couts[i] * cins[i] * 9 / 8;
    }
    WA.total = start;
    wprep_kernel<<<dim3((start + 255) / 256), 256, 0, stream>>>(WA);
  }

  // ---- fused styles (14) ----
  {
    StyleArgs SA;
    SA.d[0] = {sw0, sb0, 0, 512};
    SA.d[1] = {swr0, sbr0, 1, 512};
    for (int l = 0; l < 4; l++) {
      int c = NFa[l + 1];
      SA.d[2 + l * 3] = {swu[l], sbu[l], rowu[l], cprev0[l]};
      SA.d[3 + l * 3] = {swc[l], sbc[l], 5, c};
      SA.d[4 + l * 3] = {swr[l], sbr[l], 6, c};
    }
    style_all_kernel<<<dim3(56), 256, 0, stream>>>(latents, SA, S);
  }

  // ---- W2 ----
  int w2off[9];
  {
    W2Args WA2;
    int start = 0, off = 0;
    for (int i = 0; i < 9; i++) {
      w2off[i] = off;
      WA2.d[i] = {cw[i], cinL[i], coutL[i], start, off};
      int elems = 1 << (cinL[i] + coutL[i]);
      start += elems >> 2;
      off += elems;
    }
    WA2.total4 = start;
    w2_kernel<<<dim3((start + 255) / 256), 256, 0, stream>>>(WA2, W2);
  }

  // ---- demod2 ----
  {
    D2Args DA;
    int start = 0;
    for (int i = 0; i < 9; i++) {
      int cout = 1 << coutL[i];
      DA.d[i] = {w2off[i], sidOf[i], didOf[i], 1 << cinL[i], cout, start};
      start += B * (cout >> 6);
    }
    demod2_all_kernel<<<dim3(start), 256, 0, stream>>>(DA, W2, S, D);
  }

  // ---- conv0 (4x4, split-K z=16, chunk 32) + epi + rgb0 ----
  modconv_splitk_kernel<4, 8><<<dim3(4, B, 16), 256, (size_t)3 * 6 * 32 * 4, stream>>>(
      cnst, 0, 4, 4, 9, 512, w0, S, P);
  splitk_epi_kernel<<<dim3((32 * 512 + 255) / 256), 256, 0, stream>>>(
      P, 16, 32, 512, 16, D, b0, noise0, ns0, bufA, 1);
  rgb_kernel<<<dim3(16, B), 64, 0, stream>>>(bufA, 4, 4, 512, wr0, br0, S + 1024, nullptr, rgbA);

  // ---- level 1 (8x8, split-K) ----
  blur_up_kernel<<<dim3(64, B), 256, 0, stream>>>(bufA, 4, 4, 512, bufB);
  // u1: Cin=512, z=16, chunk 32; Cout=128 -> 128-thread blocks
  modconv_splitk_kernel<8, 8><<<dim3(8, B, 16), 128, (size_t)3 * 10 * 32 * 4, stream>>>(
      bufB, (size_t)64 * 512, 8, 8, 9, 128, wu[0], S + 2 * 1024, P);
  splitk_epi_kernel<<<dim3((128 * 128 + 255) / 256), 256, 0, stream>>>(
      P, 16, 128, 128, 64, D + 1 * 1024, bu[0], nullptr, nullptr, bufA, 0);
  // c1: Cin=128, z=8, chunk 16
  modconv_splitk_kernel<8, 4><<<dim3(8, B, 8), 128, (size_t)3 * 10 * 16 * 4, stream>>>(
      bufA, (size_t)64 * 128, 8, 8, 7, 128, wc[0], S + 3 * 1024, P);
  splitk_epi_kernel<<<dim3((128 * 128 + 255) / 256), 256, 0, stream>>>(
      P, 8, 128, 128, 64, D + 2 * 1024, bc[0], nullptr, nullptr, bufB, 0);
  rgb_kernel<<<dim3(64, B), 64, 0, stream>>>(bufB, 8, 8, 128, wr[0], br_[0], S + 4 * 1024, rgbA, rgbB);

  // ---- levels 2..4 (MFMA path) ----
  float* ybuf[4] = {bufB, bufA, bufB, bufA};
  float* rgbp = rgbB;
  const float* ysrc = bufB;
  int Hc = 8;
  for (int l = 1; l < 4; l++) {
    int c = NFa[l + 1];
    int cp = cprev0[l];
    int H2 = Hc * 2;
    int WLOG = (H2 == 16) ? 4 : (H2 == 32) ? 5 : 6;
    int wi = (l - 1) * 2;
    prep_up_kernel<<<dim3(H2 * H2, B), 256, 0, stream>>>(
        ysrc, Hc, cp, S + (2 + l * 3) * 1024, xprepA);
    {
      int PRu = (128 >> WLOG) + 2, PCu = H2 + 2;
      size_t lds = (size_t)(PRu * PCu * 40 + 64 * 296) * 2;
      mfma_conv_kernel<<<dim3((B * H2 * H2) / 128, c >> 6), 256, lds, stream>>>(
          xprepA, H2, WLOG, cp, c, wT[wi], bu[l], D + (1 + l * 2) * 1024,
          nullptr, xprepB, S + (3 + l * 3) * 1024);
    }
    float* yo = ybuf[l];
    {
      int PRu = (128 >> WLOG) + 2, PCu = H2 + 2;
      size_t lds = (size_t)(PRu * PCu * 40 + 64 * 296) * 2;
      mfma_conv_kernel<<<dim3((B * H2 * H2) / 128, c >> 6), 256, lds, stream>>>(
          xprepB, H2, WLOG, c, c, wT[wi + 1], bc[l], D + (2 + l * 2) * 1024,
          yo, nullptr, nullptr);
    }
    float* rout = (l == 3) ? (float*)d_out : ((rgbp == rgbA) ? rgbB : rgbA);
    rgb_kernel<<<dim3(H2 * H2, B), 64, 0, stream>>>(
        yo, H2, H2, c, wr[l], br_[l], S + (4 + l * 3) * 1024, rgbp, rout);
    rgbp = (rout == rgbA) ? rgbA : rgbB;
    ysrc = yo;
    Hc = H2;
  }
  (void)in_sizes; (void)n_in; (void)out_size; (void)ws_size;
}